// Round 3
// baseline (284.332 us; speedup 1.0000x reference)
//
#include <hip/hip_runtime.h>
#include <hip/hip_bf16.h>
#include <cstdint>
#include <cstddef>

#define B_DIM 2048
#define D_DIM 512
#define NROWS 12288        // 6B rows of z
#define HALF  6144         // 3B
#define NT256 48           // 256-row tiles per dim
#define NPAIR256 1176      // 48*49/2
#define EXP_SCALE 2.8853900817779268f   // log2(e)/TEMP, TEMP=0.5

typedef __attribute__((ext_vector_type(8))) __bf16 bf16x8;
typedef __attribute__((ext_vector_type(4))) float f32x4;

__device__ __forceinline__ unsigned short f2bf(float x) {
  __hip_bfloat16 h = __float2bfloat16(x);
  return *reinterpret_cast<unsigned short*>(&h);
}

__device__ __forceinline__ void gload_lds16(const void* g, void* l) {
  __builtin_amdgcn_global_load_lds(
      (const __attribute__((address_space(1))) unsigned int*)g,
      (__attribute__((address_space(3))) unsigned int*)l,
      16, 0, 0);
}

// ---------------- gather f -> Abig bf16 [12288 x 1024] ----------------
__global__ __launch_bounds__(256) void gather_convert(
    const float* __restrict__ f_seq, const float* __restrict__ f_spa,
    __hip_bfloat16* __restrict__ Abig) {
  int t = blockIdx.x * 256 + threadIdx.x;   // one thread per 4 elems
  int r = t >> 8;
  int k = (t & 255) << 2;
  const float* f = (r < HALF) ? f_spa : f_seq;
  int rr = (r < HALF) ? r : r - HALF;
  int p = rr >> 11;           // /2048
  int i = rr & 2047;
  int sel = (p == 2) ? 3 : p;
  const float* src;
  if (k < D_DIM) src = f + ((size_t)i * 4 + sel) * D_DIM + k;
  else           src = f + ((size_t)i * 4 + 2) * D_DIM + (k - D_DIM);
  float4 xv = *(const float4*)src;
  uint2 o;
  o.x = (unsigned int)f2bf(xv.x) | ((unsigned int)f2bf(xv.y) << 16);
  o.y = (unsigned int)f2bf(xv.z) | ((unsigned int)f2bf(xv.w) << 16);
  *(uint2*)(Abig + (size_t)r * 1024 + k) = o;
}

// ---------------- W [1024x512] -> Wt bf16 [512 x 1024] (transposed) ----
__global__ __launch_bounds__(256) void wt_convert(
    const float* __restrict__ W, __hip_bfloat16* __restrict__ Wt) {
  int t = blockIdx.x * 256 + threadIdx.x;   // per 4 elems of Wt
  int n = t >> 8;
  int k = (t & 255) << 2;
  float x0 = W[(size_t)(k + 0) * 512 + n];
  float x1 = W[(size_t)(k + 1) * 512 + n];
  float x2 = W[(size_t)(k + 2) * 512 + n];
  float x3 = W[(size_t)(k + 3) * 512 + n];
  uint2 o;
  o.x = (unsigned int)f2bf(x0) | ((unsigned int)f2bf(x1) << 16);
  o.y = (unsigned int)f2bf(x2) | ((unsigned int)f2bf(x3) << 16);
  *(uint2*)(Wt + (size_t)n * 1024 + k) = o;
}

// ---------------- 128x128 MFMA tile core for proj (C = A @ B^T) ----
// LDS layout: [chunk g 0..3][row 0..127][8 bf16]; conflict-free reads.
template<int STRIDE>
__device__ __forceinline__ void gemm_tile_128(
    const __hip_bfloat16* Arows, const __hip_bfloat16* Brows, int K,
    __hip_bfloat16* As, __hip_bfloat16* Bs, f32x4 acc[4][4], int tid) {
  int w = tid >> 6, lane = tid & 63;
  int wr = w >> 1, wc = w & 1;
  int g = lane >> 4, l16 = lane & 15;
  int row0 = tid & 127, ch0 = tid >> 7;
  for (int kt = 0; kt < K; kt += 32) {
    gload_lds16(Arows + (size_t)row0 * STRIDE + kt + ch0 * 8, As + w * 512);
    gload_lds16(Arows + (size_t)row0 * STRIDE + kt + (ch0 + 2) * 8, As + 2048 + w * 512);
    gload_lds16(Brows + (size_t)row0 * STRIDE + kt + ch0 * 8, Bs + w * 512);
    gload_lds16(Brows + (size_t)row0 * STRIDE + kt + (ch0 + 2) * 8, Bs + 2048 + w * 512);
    __syncthreads();
    bf16x8 af[4], bfr[4];
#pragma unroll
    for (int mi = 0; mi < 4; ++mi)
      af[mi] = *(const bf16x8*)(As + g * 1024 + (wr * 64 + mi * 16 + l16) * 8);
#pragma unroll
    for (int ni = 0; ni < 4; ++ni)
      bfr[ni] = *(const bf16x8*)(Bs + g * 1024 + (wc * 64 + ni * 16 + l16) * 8);
#pragma unroll
    for (int mi = 0; mi < 4; ++mi)
#pragma unroll
      for (int ni = 0; ni < 4; ++ni)
        acc[mi][ni] = __builtin_amdgcn_mfma_f32_16x16x32_bf16(af[mi], bfr[ni], acc[mi][ni], 0, 0, 0);
    __syncthreads();
  }
}

// ---------------- projection GEMM: v = Abig @ Wt^T + b  (fp32 out) ----
__global__ __launch_bounds__(256) void proj_gemm(
    const __hip_bfloat16* __restrict__ Abig, const __hip_bfloat16* __restrict__ Wt,
    const float* __restrict__ bvec, float* __restrict__ v) {
  __shared__ __align__(16) __hip_bfloat16 As[4096], Bs[4096];
  int bn = blockIdx.x, bm = blockIdx.y;
  f32x4 acc[4][4];
#pragma unroll
  for (int i = 0; i < 4; ++i)
#pragma unroll
    for (int j = 0; j < 4; ++j) acc[i][j] = (f32x4){0.f, 0.f, 0.f, 0.f};
  int tid = threadIdx.x;
  gemm_tile_128<1024>(Abig + (size_t)bm * 128 * 1024, Wt + (size_t)bn * 128 * 1024,
                      1024, As, Bs, acc, tid);
  int w = tid >> 6, lane = tid & 63, wr = w >> 1, wc = w & 1, g = lane >> 4, l16 = lane & 15;
#pragma unroll
  for (int mi = 0; mi < 4; ++mi)
#pragma unroll
    for (int ni = 0; ni < 4; ++ni)
#pragma unroll
      for (int reg = 0; reg < 4; ++reg) {
        int grow = bm * 128 + wr * 64 + mi * 16 + g * 4 + reg;
        int gcol = bn * 128 + wc * 64 + ni * 16 + l16;
        v[(size_t)grow * 512 + gcol] = acc[mi][ni][reg] + bvec[gcol];
      }
}

// ---------------- row L2-normalize: z = v / max(||v||, eps) as bf16 ----
__global__ __launch_bounds__(256) void normalize_rows(
    const float* __restrict__ v, __hip_bfloat16* __restrict__ z) {
  int r = blockIdx.x;
  int tid = threadIdx.x;
  const float* vr = v + (size_t)r * 512;
  float2 xv = *(const float2*)(vr + tid * 2);
  float s = xv.x * xv.x + xv.y * xv.y;
#pragma unroll
  for (int m = 1; m < 64; m <<= 1) s += __shfl_xor(s, m);
  __shared__ float ws4[4];
  int w = tid >> 6, lane = tid & 63;
  if (lane == 0) ws4[w] = s;
  __syncthreads();
  float tot = ws4[0] + ws4[1] + ws4[2] + ws4[3];
  float inv = 1.0f / fmaxf(sqrtf(tot), 1e-12f);
  unsigned int o = (unsigned int)f2bf(xv.x * inv) | ((unsigned int)f2bf(xv.y * inv) << 16);
  *(unsigned int*)(z + (size_t)r * 512 + tid * 2) = o;
}

// ==== fused symmetric sim: 256^2 tile, 8-phase, counted vmcnt =========
// 512 thr = 8 waves (2 wave-rows x 4 wave-cols); per-wave out 128x64.
// LDS per K-tile (BK=64): A,B each [chunk c 0..7][row 0..255][8 bf16] =32KB,
// double-buffered = 128KB total. Staged via global_load_lds (linear dest).
#define SIM_SMEM 137216
__global__ __launch_bounds__(512, 2) void sim_fused_256(
    const __hip_bfloat16* __restrict__ z, float* __restrict__ partial,
    float* __restrict__ possim, float* __restrict__ selfsim) {
  extern __shared__ __align__(16) char smem[];
  __hip_bfloat16* Ab = (__hip_bfloat16*)smem;             // [2][16384]
  __hip_bfloat16* Bb = (__hip_bfloat16*)(smem + 65536);   // [2][16384]
  float* wsum = (float*)(smem + 131072);                  // [4][256]
  float* csum = (float*)(smem + 135168);                  // [2][256]

  // --- block -> (bi,bj): supertile(6x6)-major order, XCD-chunked ---
  // q = supertile-ordered tile index; XCD x=blockIdx%8 gets q in [x*147,(x+1)*147)
  int l = blockIdx.x;
  int q = (l & 7) * 147 + (l >> 3);
  int si = 0, sj = 0, jj = q;
  for (;;) {
    int cnt = (si == sj) ? 21 : 36;
    if (jj < cnt) break;
    jj -= cnt;
    ++sj;
    if (sj == 8) { ++si; sj = si; }
  }
  int bi, bj;
  if (si == sj) {
    int r = 0;
    while (jj >= 6 - r) { jj -= 6 - r; ++r; }
    bi = si * 6 + r; bj = si * 6 + r + jj;
  } else {
    bi = si * 6 + jj / 6; bj = sj * 6 + jj % 6;
  }

  const __hip_bfloat16* zA = z + (size_t)bi * 256 * 512;
  const __hip_bfloat16* zB = z + (size_t)bj * 256 * 512;
  int tid = threadIdx.x;
  int lane = tid & 63;
  int w = tid >> 6, wr = w >> 2, wc = w & 3;
  int g2 = lane >> 4, l16 = lane & 15;
  int wrow = wr * 128, wcol = wc * 64;
  int wbase = tid & 0x1C0;                                // w*64
  const size_t srcoff = (size_t)(tid & 255) * 512 + (size_t)(tid >> 8) * 8;
  const int aoff0 = g2 * 2048 + (wrow + l16) * 8;
  const int boff0 = g2 * 2048 + (wcol + l16) * 8;

  f32x4 acc[8][4];
#pragma unroll
  for (int i = 0; i < 8; ++i)
#pragma unroll
    for (int j = 0; j < 4; ++j) acc[i][j] = (f32x4){0.f, 0.f, 0.f, 0.f};

#define STAGE(P, KT1, An, Bn) do { \
    gload_lds16(zA + srcoff + (KT1) + (P) * 16, (An) + ((P) * 512 + wbase) * 8); \
    gload_lds16(zB + srcoff + (KT1) + (P) * 16, (Bn) + ((P) * 512 + wbase) * 8); \
  } while (0)

#define PHASE(MI4, H, P) do { \
    bf16x8 af[4]; \
    _Pragma("unroll") \
    for (int m = 0; m < 4; ++m) \
      af[m] = *(const bf16x8*)(Acur + aoff0 + (H) * 8192 + ((MI4) * 4 + m) * 128); \
    if ((MI4) == 0) { \
      _Pragma("unroll") \
      for (int n = 0; n < 4; ++n) \
        bfr[n] = *(const bf16x8*)(Bcur + boff0 + (H) * 8192 + n * 128); \
    } \
    if (stage_on) STAGE(P, ktn, Anx, Bnx); \
    __builtin_amdgcn_s_barrier(); \
    __builtin_amdgcn_s_setprio(1); \
    _Pragma("unroll") \
    for (int m = 0; m < 4; ++m) \
      _Pragma("unroll") \
      for (int n = 0; n < 4; ++n) \
        acc[(MI4) * 4 + m][n] = __builtin_amdgcn_mfma_f32_16x16x32_bf16( \
            af[m], bfr[n], acc[(MI4) * 4 + m][n], 0, 0, 0); \
    __builtin_amdgcn_s_setprio(0); \
    __builtin_amdgcn_s_barrier(); \
  } while (0)

  // prologue: stage K-tile 0 into buf0
  STAGE(0, 0, Ab, Bb); STAGE(1, 0, Ab, Bb); STAGE(2, 0, Ab, Bb); STAGE(3, 0, Ab, Bb);
  asm volatile("s_waitcnt vmcnt(0)" ::: "memory");
  __builtin_amdgcn_s_barrier();

#pragma unroll 2
  for (int t = 0; t < 8; ++t) {
    const __hip_bfloat16* Acur = Ab + (t & 1) * 16384;
    const __hip_bfloat16* Bcur = Bb + (t & 1) * 16384;
    __hip_bfloat16* Anx = Ab + ((t + 1) & 1) * 16384;
    __hip_bfloat16* Bnx = Bb + ((t + 1) & 1) * 16384;
    int ktn = (t + 1) * 64;
    bool stage_on = (t < 7);
    bf16x8 bfr[4];
    PHASE(0, 0, 0);
    PHASE(1, 0, 1);
    PHASE(0, 1, 2);
    PHASE(1, 1, 3);
    if (t < 7) asm volatile("s_waitcnt vmcnt(0)" ::: "memory");
    __builtin_amdgcn_s_barrier();
  }
#undef PHASE
#undef STAGE

  // --- epilogue ---
  bool diag = (bi == bj), posT = (bj == bi + 24);
  if (diag || posT) {
#pragma unroll
    for (int mi = 0; mi < 8; ++mi) {
      int qq = wr * 8 + mi;
      if (wc == (qq >> 2)) {
        int ni = qq & 3;
#pragma unroll
        for (int nn = 0; nn < 4; ++nn)
          if (nn == ni) {
#pragma unroll
            for (int reg = 0; reg < 4; ++reg)
              if (l16 == g2 * 4 + reg) {
                int rl = wrow + mi * 16 + g2 * 4 + reg;
                float sv = acc[mi][nn][reg];
                if (diag) selfsim[bi * 256 + rl] = sv;
                else      possim[bi * 256 + rl] = sv;
              }
          }
      }
    }
  }
  // exp in place
#pragma unroll
  for (int mi = 0; mi < 8; ++mi)
#pragma unroll
    for (int ni = 0; ni < 4; ++ni)
#pragma unroll
      for (int reg = 0; reg < 4; ++reg)
        acc[mi][ni][reg] = exp2f(acc[mi][ni][reg] * EXP_SCALE);
  // row sums: in-thread over ni, reduce over l16 (bits 0..3)
#pragma unroll
  for (int mi = 0; mi < 8; ++mi)
#pragma unroll
    for (int reg = 0; reg < 4; ++reg) {
      float s = acc[mi][0][reg] + acc[mi][1][reg] + acc[mi][2][reg] + acc[mi][3][reg];
#pragma unroll
      for (int msk = 1; msk < 16; msk <<= 1) s += __shfl_xor(s, msk);
      if (l16 == 0) wsum[wc * 256 + wrow + mi * 16 + g2 * 4 + reg] = s;
    }
  // col sums: in-thread over mi,reg, reduce over g2 (bits 4..5)
  float cs[4];
#pragma unroll
  for (int ni = 0; ni < 4; ++ni) {
    float s = 0.f;
#pragma unroll
    for (int mi = 0; mi < 8; ++mi)
#pragma unroll
      for (int reg = 0; reg < 4; ++reg) s += acc[mi][ni][reg];
    s += __shfl_xor(s, 16);
    s += __shfl_xor(s, 32);
    cs[ni] = s;
  }
  if (lane < 16) {
#pragma unroll
    for (int ni = 0; ni < 4; ++ni)
      csum[wr * 256 + wcol + ni * 16 + l16] = cs[ni];
  }
  __syncthreads();
  if (tid < 256) {
    float rtot = wsum[tid] + wsum[256 + tid] + wsum[512 + tid] + wsum[768 + tid];
    partial[(size_t)bj * NROWS + bi * 256 + tid] = rtot;
    if (!diag) {
      float ctot = csum[tid] + csum[256 + tid];
      partial[(size_t)bi * NROWS + bj * 256 + tid] = ctot;
    }
  }
}

// ---------------- per-row term ----------------
__global__ __launch_bounds__(256) void finalize_terms(
    const float* __restrict__ partial, const float* __restrict__ possim,
    const float* __restrict__ selfsim, float* __restrict__ terms) {
  int i = blockIdx.x * 256 + threadIdx.x;
  float s = 0.f;
  for (int bjt = 0; bjt < NT256; ++bjt) s += partial[(size_t)bjt * NROWS + i];
  float denom = s - exp2f(selfsim[i] * EXP_SCALE);
  float pos = possim[(i < HALF) ? i : (i - HALF)];
  terms[i] = -2.0f * pos + logf(denom);
}

// ---------------- deterministic single-block sum ----------------
__global__ __launch_bounds__(256) void finalize_sum(
    const float* __restrict__ terms, float* __restrict__ out) {
  int tid = threadIdx.x;
  float s = 0.f;
  for (int i = tid; i < NROWS; i += 256) s += terms[i];
#pragma unroll
  for (int m = 1; m < 64; m <<= 1) s += __shfl_xor(s, m);
  __shared__ float ws4[4];
  int w = tid >> 6, lane = tid & 63;
  if (lane == 0) ws4[w] = s;
  __syncthreads();
  if (tid == 0) out[0] = (ws4[0] + ws4[1] + ws4[2] + ws4[3]) / 12288.0f;
}

extern "C" void kernel_launch(void* const* d_in, const int* in_sizes, int n_in,
                              void* d_out, int out_size, void* d_ws, size_t ws_size,
                              hipStream_t stream) {
  const float* f_seq = (const float*)d_in[0];
  const float* f_spa = (const float*)d_in[1];
  const float* W     = (const float*)d_in[2];
  const float* b     = (const float*)d_in[3];
  char* ws = (char*)d_ws;
  __hip_bfloat16* Abig = (__hip_bfloat16*)ws;                // 25165824 B
  __hip_bfloat16* Wt   = (__hip_bfloat16*)(ws + 25165824);   // 1048576 B
  float* v             = (float*)(ws + 26214400);            // 25165824 B
  __hip_bfloat16* z    = (__hip_bfloat16*)ws;                // alias over dead Abig
  float* partial       = (float*)(ws + 12582912);            // 48*12288*4 = 2359296
  float* possim        = (float*)(ws + 14942208);            // 6144*4
  float* selfsim       = (float*)(ws + 14966784);            // 12288*4
  float* terms         = (float*)(ws + 15015936);            // 12288*4
  float* out           = (float*)d_out;

  static bool attr_set = false;
  hipFuncSetAttribute((const void*)sim_fused_256,
                      hipFuncAttributeMaxDynamicSharedMemorySize, SIM_SMEM);
  (void)attr_set;

  gather_convert<<<dim3(12288), dim3(256), 0, stream>>>(f_seq, f_spa, Abig);
  wt_convert<<<dim3(512), dim3(256), 0, stream>>>(W, Wt);
  proj_gemm<<<dim3(4, 96), dim3(256), 0, stream>>>(Abig, Wt, b, v);
  normalize_rows<<<dim3(12288), dim3(256), 0, stream>>>(v, z);
  sim_fused_256<<<dim3(NPAIR256), dim3(512), SIM_SMEM, stream>>>(z, partial, possim, selfsim);
  finalize_terms<<<dim3(48), dim3(256), 0, stream>>>(partial, possim, selfsim, terms);
  finalize_sum<<<dim3(1), dim3(256), 0, stream>>>(terms, out);
}

// Round 4
// 197.735 us; speedup vs baseline: 1.4379x; 1.4379x over previous
//
#include <hip/hip_runtime.h>
#include <hip/hip_bf16.h>
#include <cstdint>
#include <cstddef>

#define B_DIM 2048
#define D_DIM 512
#define NROWS 12288        // 6B rows of z
#define HALF  6144         // 3B
#define NT256 48           // 256-row tiles per dim
#define NPAIR256 1176      // 48*49/2
#define EXP_SCALE 2.8853900817779268f   // log2(e)/TEMP, TEMP=0.5

typedef __attribute__((ext_vector_type(8))) __bf16 bf16x8;
typedef __attribute__((ext_vector_type(4))) float f32x4;

__device__ __forceinline__ unsigned short f2bf(float x) {
  __hip_bfloat16 h = __float2bfloat16(x);
  return *reinterpret_cast<unsigned short*>(&h);
}

__device__ __forceinline__ void gload_lds16(const void* g, void* l) {
  __builtin_amdgcn_global_load_lds(
      (const __attribute__((address_space(1))) unsigned int*)g,
      (__attribute__((address_space(3))) unsigned int*)l,
      16, 0, 0);
}

// ---- gather f -> Abig_perm bf16: [panel r/128][chunk k/8][row r%128][8] ----
// row r (<HALF: f_spa else f_seq), p=rr/B, i=rr%B, sel={0,1,3}[p];
// A[r][k] = k<512 ? f[i,sel,k] : f[i,2,k-512]. One thread per 8-elem chunk.
__global__ __launch_bounds__(256) void gather_convert(
    const float* __restrict__ f_seq, const float* __restrict__ f_spa,
    __hip_bfloat16* __restrict__ Abig) {
  int gidx = blockIdx.x * 256 + threadIdx.x;   // 12288*128 granules
  int r = gidx >> 7;
  int c = gidx & 127;
  int k = c << 3;
  const float* f = (r < HALF) ? f_spa : f_seq;
  int rr = (r < HALF) ? r : r - HALF;
  int p = rr >> 11;
  int i = rr & 2047;
  int sel = (p == 2) ? 3 : p;
  const float* src;
  if (k < D_DIM) src = f + ((size_t)i * 4 + sel) * D_DIM + k;
  else           src = f + ((size_t)i * 4 + 2) * D_DIM + (k - D_DIM);
  float4 x0 = *(const float4*)src;
  float4 x1 = *(const float4*)(src + 4);
  uint4 o;
  o.x = (unsigned int)f2bf(x0.x) | ((unsigned int)f2bf(x0.y) << 16);
  o.y = (unsigned int)f2bf(x0.z) | ((unsigned int)f2bf(x0.w) << 16);
  o.z = (unsigned int)f2bf(x1.x) | ((unsigned int)f2bf(x1.y) << 16);
  o.w = (unsigned int)f2bf(x1.z) | ((unsigned int)f2bf(x1.w) << 16);
  // dest: panel (r>>7) * 131072 + c*1024 + (r&127)*8
  *(uint4*)(Abig + (size_t)(r >> 7) * 131072 + c * 1024 + (r & 127) * 8) = o;
}

// ---- W [1024x512] -> Wt_perm: [panel n/128][chunk k/8][row n%128][8] ----
__global__ __launch_bounds__(256) void wt_convert(
    const float* __restrict__ W, __hip_bfloat16* __restrict__ Wt) {
  int gidx = blockIdx.x * 256 + threadIdx.x;   // 512*128 granules
  int n = gidx >> 7;
  int c = gidx & 127;
  int k = c << 3;
  unsigned int oo[4];
#pragma unroll
  for (int h = 0; h < 4; ++h) {
    float a = W[(size_t)(k + 2 * h) * 512 + n];
    float b = W[(size_t)(k + 2 * h + 1) * 512 + n];
    oo[h] = (unsigned int)f2bf(a) | ((unsigned int)f2bf(b) << 16);
  }
  uint4 o = {oo[0], oo[1], oo[2], oo[3]};
  *(uint4*)(Wt + (size_t)(n >> 7) * 131072 + c * 1024 + (n & 127) * 8) = o;
}

// ---- 128x128 proj tile core; panels chunk-major, fully linear staging ----
// LDS [chunk 0..3][row 0..127][8 bf16] per K-step of 32; conflict-free.
__device__ __forceinline__ void gemm_tile_128p(
    const __hip_bfloat16* Ap, const __hip_bfloat16* Bp, int nkt,
    __hip_bfloat16* As, __hip_bfloat16* Bs, f32x4 acc[4][4], int tid) {
  int w = tid >> 6, lane = tid & 63;
  int wr = w >> 1, wc = w & 1;
  int g = lane >> 4, l16 = lane & 15;
  int wb = (tid & 0xC0) * 8;
  for (int t = 0; t < nkt; ++t) {
    gload_lds16(Ap + (size_t)t * 4096 + (size_t)tid * 8,         As + wb);
    gload_lds16(Ap + (size_t)t * 4096 + (size_t)(256 + tid) * 8, As + 2048 + wb);
    gload_lds16(Bp + (size_t)t * 4096 + (size_t)tid * 8,         Bs + wb);
    gload_lds16(Bp + (size_t)t * 4096 + (size_t)(256 + tid) * 8, Bs + 2048 + wb);
    __syncthreads();
    bf16x8 af[4], bfr[4];
#pragma unroll
    for (int mi = 0; mi < 4; ++mi)
      af[mi] = *(const bf16x8*)(As + g * 1024 + (wr * 64 + mi * 16 + l16) * 8);
#pragma unroll
    for (int ni = 0; ni < 4; ++ni)
      bfr[ni] = *(const bf16x8*)(Bs + g * 1024 + (wc * 64 + ni * 16 + l16) * 8);
#pragma unroll
    for (int mi = 0; mi < 4; ++mi)
#pragma unroll
      for (int ni = 0; ni < 4; ++ni)
        acc[mi][ni] = __builtin_amdgcn_mfma_f32_16x16x32_bf16(af[mi], bfr[ni], acc[mi][ni], 0, 0, 0);
    __syncthreads();
  }
}

// ---------------- projection GEMM: v = A @ Wt^T + b  (fp32 out) ----
__global__ __launch_bounds__(256) void proj_gemm(
    const __hip_bfloat16* __restrict__ Abig, const __hip_bfloat16* __restrict__ Wt,
    const float* __restrict__ bvec, float* __restrict__ v) {
  __shared__ __align__(16) __hip_bfloat16 As[4096], Bs[4096];
  int bn = blockIdx.x, bm = blockIdx.y;
  f32x4 acc[4][4];
#pragma unroll
  for (int i = 0; i < 4; ++i)
#pragma unroll
    for (int j = 0; j < 4; ++j) acc[i][j] = (f32x4){0.f, 0.f, 0.f, 0.f};
  int tid = threadIdx.x;
  gemm_tile_128p(Abig + (size_t)bm * 131072, Wt + (size_t)bn * 131072,
                 32, As, Bs, acc, tid);
  int w = tid >> 6, lane = tid & 63, wr = w >> 1, wc = w & 1, g = lane >> 4, l16 = lane & 15;
#pragma unroll
  for (int mi = 0; mi < 4; ++mi)
#pragma unroll
    for (int ni = 0; ni < 4; ++ni)
#pragma unroll
      for (int reg = 0; reg < 4; ++reg) {
        int grow = bm * 128 + wr * 64 + mi * 16 + g * 4 + reg;
        int gcol = bn * 128 + wc * 64 + ni * 16 + l16;
        v[(size_t)grow * 512 + gcol] = acc[mi][ni][reg] + bvec[gcol];
      }
}

// -- row L2-normalize; writes z_perm [panel r/256][chunk k/8][row r%256][8] --
__global__ __launch_bounds__(256) void normalize_rows(
    const float* __restrict__ v, __hip_bfloat16* __restrict__ z) {
  int r = blockIdx.x;
  int tid = threadIdx.x;
  const float* vr = v + (size_t)r * 512;
  float2 xv = *(const float2*)(vr + tid * 2);
  float s = xv.x * xv.x + xv.y * xv.y;
#pragma unroll
  for (int m = 1; m < 64; m <<= 1) s += __shfl_xor(s, m);
  __shared__ float ws4[4];
  int w = tid >> 6, lane = tid & 63;
  if (lane == 0) ws4[w] = s;
  __syncthreads();
  float tot = ws4[0] + ws4[1] + ws4[2] + ws4[3];
  float inv = 1.0f / fmaxf(sqrtf(tot), 1e-12f);
  unsigned int o = (unsigned int)f2bf(xv.x * inv) | ((unsigned int)f2bf(xv.y * inv) << 16);
  // k = 2*tid -> chunk c = tid>>2, elem e = (tid&3)*2
  *(unsigned int*)(z + (size_t)(r >> 8) * 131072 + (tid >> 2) * 2048 +
                   (r & 255) * 8 + (tid & 3) * 2) = o;
}

// ==== fused symmetric sim: 256^2 tile, 4-phase/K-tile, counted vmcnt ====
// 512 thr = 8 waves (2 x 4); per-wave out 128x64. z_perm panels make staging
// fully linear on BOTH sides. LDS A,B: [chunk 0..7][row 0..255][8] = 32KB
// each, double-buffered = 128KB. Counted vmcnt: 8 loads/wave/tile; rounds
// 0-1 (H0) waited at tile swap vmcnt(4), rounds 2-3 (H1) at mid-tile vmcnt(8).
#define SIM_SMEM 137216
__global__ __launch_bounds__(512, 2) void sim_fused_256(
    const __hip_bfloat16* __restrict__ z, float* __restrict__ partial,
    float* __restrict__ possim, float* __restrict__ selfsim) {
  extern __shared__ __align__(16) char smem[];
  __hip_bfloat16* Ab = (__hip_bfloat16*)smem;             // [2][16384]
  __hip_bfloat16* Bb = (__hip_bfloat16*)(smem + 65536);   // [2][16384]
  float* wsum = (float*)(smem + 131072);                  // [4][256]
  float* csum = (float*)(smem + 135168);                  // [2][256]

  // --- block -> (bi,bj): supertile(6x6)-major order, XCD-chunked ---
  int l = blockIdx.x;
  int q = (l & 7) * 147 + (l >> 3);
  int si = 0, sj = 0, jj = q;
  for (;;) {
    int cnt = (si == sj) ? 21 : 36;
    if (jj < cnt) break;
    jj -= cnt;
    ++sj;
    if (sj == 8) { ++si; sj = si; }
  }
  int bi, bj;
  if (si == sj) {
    int rr = 0;
    while (jj >= 6 - rr) { jj -= 6 - rr; ++rr; }
    bi = si * 6 + rr; bj = si * 6 + rr + jj;
  } else {
    bi = si * 6 + jj / 6; bj = sj * 6 + jj % 6;
  }

  const __hip_bfloat16* zAp = z + (size_t)bi * 131072;
  const __hip_bfloat16* zBp = z + (size_t)bj * 131072;
  int tid = threadIdx.x;
  int lane = tid & 63;
  int w = tid >> 6, wr = w >> 2, wc = w & 3;
  int g2 = lane >> 4, l16 = lane & 15;
  int wrow = wr * 128, wcol = wc * 64;
  const int ldst = (tid & 0x1C0) * 8;          // wave-uniform dest base (elems)

  f32x4 acc[8][4];
#pragma unroll
  for (int i = 0; i < 8; ++i)
#pragma unroll
    for (int j = 0; j < 4; ++j) acc[i][j] = (f32x4){0.f, 0.f, 0.f, 0.f};

#define STAGE(R, TT, An, Bn) do { \
    gload_lds16(zAp + (size_t)(TT) * 16384 + ((R) * 512 + tid) * 8, (An) + (R) * 4096 + ldst); \
    gload_lds16(zBp + (size_t)(TT) * 16384 + ((R) * 512 + tid) * 8, (Bn) + (R) * 4096 + ldst); \
  } while (0)

  // PHASE: ds_read frags -> optional stage -> barrier -> MFMA -> optional wait -> barrier
#define PHASE(MI4, H, DO_ST, R0, R1, WN) do { \
    bf16x8 af[4]; \
    _Pragma("unroll") \
    for (int m = 0; m < 4; ++m) \
      af[m] = *(const bf16x8*)(Acur + (H) * 8192 + g2 * 2048 + (wrow + ((MI4) * 4 + m) * 16 + l16) * 8); \
    if ((MI4) == 0) { \
      _Pragma("unroll") \
      for (int n = 0; n < 4; ++n) \
        bfr[n] = *(const bf16x8*)(Bcur + (H) * 8192 + g2 * 2048 + (wcol + n * 16 + l16) * 8); \
    } \
    if (DO_ST) { STAGE(R0, tn, Anx, Bnx); STAGE(R1, tn, Anx, Bnx); } \
    __builtin_amdgcn_s_barrier(); \
    __builtin_amdgcn_s_setprio(1); \
    _Pragma("unroll") \
    for (int m = 0; m < 4; ++m) \
      _Pragma("unroll") \
      for (int n = 0; n < 4; ++n) \
        acc[(MI4) * 4 + m][n] = __builtin_amdgcn_mfma_f32_16x16x32_bf16( \
            af[m], bfr[n], acc[(MI4) * 4 + m][n], 0, 0, 0); \
    __builtin_amdgcn_s_setprio(0); \
    if ((WN) == 8)      { asm volatile("s_waitcnt vmcnt(8)" ::: "memory"); } \
    else if ((WN) == 4) { asm volatile("s_waitcnt vmcnt(4)" ::: "memory"); } \
    else if ((WN) == 0) { asm volatile("s_waitcnt vmcnt(0)" ::: "memory"); } \
    __builtin_amdgcn_sched_barrier(0); \
    __builtin_amdgcn_s_barrier(); \
  } while (0)

  // prologue: stage all of K-tile 0 into buf0; wait H0 (leave H1 in flight)
  STAGE(0, 0, Ab, Bb); STAGE(1, 0, Ab, Bb); STAGE(2, 0, Ab, Bb); STAGE(3, 0, Ab, Bb);
  asm volatile("s_waitcnt vmcnt(4)" ::: "memory");
  __builtin_amdgcn_sched_barrier(0);
  __builtin_amdgcn_s_barrier();

#pragma unroll 2
  for (int t = 0; t < 8; ++t) {
    const __hip_bfloat16* Acur = Ab + (t & 1) * 16384;
    const __hip_bfloat16* Bcur = Bb + (t & 1) * 16384;
    __hip_bfloat16* Anx = Ab + ((t + 1) & 1) * 16384;
    __hip_bfloat16* Bnx = Bb + ((t + 1) & 1) * 16384;
    int tn = t + 1;
    bool st = (t < 7);
    bf16x8 bfr[4];
    PHASE(0, 0, st, 0, 1, -1);            // quadrant 0, H0; stage next r0,r1
    PHASE(1, 0, st, 2, 3, st ? 8 : 0);    // quadrant 1, H0; stage r2,r3; wait cur H1
    PHASE(0, 1, false, 0, 0, -1);         // quadrant 0, H1
    PHASE(1, 1, false, 0, 0, st ? 4 : -1);// quadrant 1, H1; wait next H0
  }
#undef PHASE
#undef STAGE

  // --- epilogue ---
  bool diag = (bi == bj), posT = (bj == bi + 24);
  if (diag || posT) {
#pragma unroll
    for (int mi = 0; mi < 8; ++mi) {
      int qq = wr * 8 + mi;
      if (wc == (qq >> 2)) {
        int ni = qq & 3;
#pragma unroll
        for (int nn = 0; nn < 4; ++nn)
          if (nn == ni) {
#pragma unroll
            for (int reg = 0; reg < 4; ++reg)
              if (l16 == g2 * 4 + reg) {
                int rl = wrow + mi * 16 + g2 * 4 + reg;
                float sv = acc[mi][nn][reg];
                if (diag) selfsim[bi * 256 + rl] = sv;
                else      possim[bi * 256 + rl] = sv;
              }
          }
      }
    }
  }
  // exp in place
#pragma unroll
  for (int mi = 0; mi < 8; ++mi)
#pragma unroll
    for (int ni = 0; ni < 4; ++ni)
#pragma unroll
      for (int reg = 0; reg < 4; ++reg)
        acc[mi][ni][reg] = exp2f(acc[mi][ni][reg] * EXP_SCALE);
  // row sums: in-thread over ni, reduce over l16 (bits 0..3)
#pragma unroll
  for (int mi = 0; mi < 8; ++mi)
#pragma unroll
    for (int reg = 0; reg < 4; ++reg) {
      float s = acc[mi][0][reg] + acc[mi][1][reg] + acc[mi][2][reg] + acc[mi][3][reg];
#pragma unroll
      for (int msk = 1; msk < 16; msk <<= 1) s += __shfl_xor(s, msk);
      if (l16 == 0) wsum[wc * 256 + wrow + mi * 16 + g2 * 4 + reg] = s;
    }
  // col sums: in-thread over mi,reg, reduce over g2 (bits 4..5)
  float cs[4];
#pragma unroll
  for (int ni = 0; ni < 4; ++ni) {
    float s = 0.f;
#pragma unroll
    for (int mi = 0; mi < 8; ++mi)
#pragma unroll
      for (int reg = 0; reg < 4; ++reg) s += acc[mi][ni][reg];
    s += __shfl_xor(s, 16);
    s += __shfl_xor(s, 32);
    cs[ni] = s;
  }
  if (lane < 16) {
#pragma unroll
    for (int ni = 0; ni < 4; ++ni)
      csum[wr * 256 + wcol + ni * 16 + l16] = cs[ni];
  }
  __syncthreads();
  if (tid < 256) {
    float rtot = wsum[tid] + wsum[256 + tid] + wsum[512 + tid] + wsum[768 + tid];
    partial[(size_t)bj * NROWS + bi * 256 + tid] = rtot;
    if (!diag) {
      float ctot = csum[tid] + csum[256 + tid];
      partial[(size_t)bi * NROWS + bj * 256 + tid] = ctot;
    }
  }
}

// ---------------- per-row term ----------------
__global__ __launch_bounds__(256) void finalize_terms(
    const float* __restrict__ partial, const float* __restrict__ possim,
    const float* __restrict__ selfsim, float* __restrict__ terms) {
  int i = blockIdx.x * 256 + threadIdx.x;
  float s = 0.f;
  for (int bjt = 0; bjt < NT256; ++bjt) s += partial[(size_t)bjt * NROWS + i];
  float denom = s - exp2f(selfsim[i] * EXP_SCALE);
  float pos = possim[(i < HALF) ? i : (i - HALF)];
  terms[i] = -2.0f * pos + logf(denom);
}

// ---------------- deterministic single-block sum ----------------
__global__ __launch_bounds__(256) void finalize_sum(
    const float* __restrict__ terms, float* __restrict__ out) {
  int tid = threadIdx.x;
  float s = 0.f;
  for (int i = tid; i < NROWS; i += 256) s += terms[i];
#pragma unroll
  for (int m = 1; m < 64; m <<= 1) s += __shfl_xor(s, m);
  __shared__ float ws4[4];
  int w = tid >> 6, lane = tid & 63;
  if (lane == 0) ws4[w] = s;
  __syncthreads();
  if (tid == 0) out[0] = (ws4[0] + ws4[1] + ws4[2] + ws4[3]) / 12288.0f;
}

extern "C" void kernel_launch(void* const* d_in, const int* in_sizes, int n_in,
                              void* d_out, int out_size, void* d_ws, size_t ws_size,
                              hipStream_t stream) {
  const float* f_seq = (const float*)d_in[0];
  const float* f_spa = (const float*)d_in[1];
  const float* W     = (const float*)d_in[2];
  const float* b     = (const float*)d_in[3];
  char* ws = (char*)d_ws;
  __hip_bfloat16* Abig = (__hip_bfloat16*)ws;                // 25165824 B
  __hip_bfloat16* Wt   = (__hip_bfloat16*)(ws + 25165824);   // 1048576 B
  float* v             = (float*)(ws + 26214400);            // 25165824 B
  __hip_bfloat16* z    = (__hip_bfloat16*)ws;                // alias over dead Abig
  float* partial       = (float*)(ws + 12582912);            // 48*12288*4 = 2359296
  float* possim        = (float*)(ws + 14942208);            // 6144*4
  float* selfsim       = (float*)(ws + 14966784);            // 12288*4
  float* terms         = (float*)(ws + 15015936);            // 12288*4
  float* out           = (float*)d_out;

  hipFuncSetAttribute((const void*)sim_fused_256,
                      hipFuncAttributeMaxDynamicSharedMemorySize, SIM_SMEM);

  gather_convert<<<dim3(6144), dim3(256), 0, stream>>>(f_seq, f_spa, Abig);
  wt_convert<<<dim3(256), dim3(256), 0, stream>>>(W, Wt);
  proj_gemm<<<dim3(4, 96), dim3(256), 0, stream>>>(Abig, Wt, b, v);
  normalize_rows<<<dim3(12288), dim3(256), 0, stream>>>(v, z);
  sim_fused_256<<<dim3(NPAIR256), dim3(512), SIM_SMEM, stream>>>(z, partial, possim, selfsim);
  finalize_terms<<<dim3(48), dim3(256), 0, stream>>>(partial, possim, selfsim, terms);
  finalize_sum<<<dim3(1), dim3(256), 0, stream>>>(terms, out);
}

// Round 5
// 175.611 us; speedup vs baseline: 1.6191x; 1.1260x over previous
//
#include <hip/hip_runtime.h>
#include <hip/hip_bf16.h>
#include <cstdint>
#include <cstddef>

#define B_DIM 2048
#define D_DIM 512
#define NROWS 12288        // 6B rows of z
#define HALF  6144         // 3B
#define NTILE 96           // 128-row tiles per dim
#define NPAIR 4656         // 96*97/2 upper-tri tiles
#define EXP_SCALE 2.8853900817779268f   // log2(e)/TEMP, TEMP=0.5

typedef __attribute__((ext_vector_type(8))) __bf16 bf16x8;
typedef __attribute__((ext_vector_type(4))) float f32x4;

__device__ __forceinline__ unsigned short f2bf(float x) {
  __hip_bfloat16 h = __float2bfloat16(x);
  return *reinterpret_cast<unsigned short*>(&h);
}

__device__ __forceinline__ void gload_lds16(const void* g, void* l) {
  __builtin_amdgcn_global_load_lds(
      (const __attribute__((address_space(1))) unsigned int*)g,
      (__attribute__((address_space(3))) unsigned int*)l,
      16, 0, 0);
}

// ---- gather f -> Abig_perm bf16: [panel r/128][chunk k/8][row r%128][8] ----
__global__ __launch_bounds__(256) void gather_convert(
    const float* __restrict__ f_seq, const float* __restrict__ f_spa,
    __hip_bfloat16* __restrict__ Abig) {
  int gidx = blockIdx.x * 256 + threadIdx.x;   // 12288*128 granules
  int r = gidx >> 7;
  int c = gidx & 127;
  int k = c << 3;
  const float* f = (r < HALF) ? f_spa : f_seq;
  int rr = (r < HALF) ? r : r - HALF;
  int p = rr >> 11;
  int i = rr & 2047;
  int sel = (p == 2) ? 3 : p;
  const float* src;
  if (k < D_DIM) src = f + ((size_t)i * 4 + sel) * D_DIM + k;
  else           src = f + ((size_t)i * 4 + 2) * D_DIM + (k - D_DIM);
  float4 x0 = *(const float4*)src;
  float4 x1 = *(const float4*)(src + 4);
  uint4 o;
  o.x = (unsigned int)f2bf(x0.x) | ((unsigned int)f2bf(x0.y) << 16);
  o.y = (unsigned int)f2bf(x0.z) | ((unsigned int)f2bf(x0.w) << 16);
  o.z = (unsigned int)f2bf(x1.x) | ((unsigned int)f2bf(x1.y) << 16);
  o.w = (unsigned int)f2bf(x1.z) | ((unsigned int)f2bf(x1.w) << 16);
  *(uint4*)(Abig + (size_t)(r >> 7) * 131072 + c * 1024 + (r & 127) * 8) = o;
}

// ---- W [1024x512] -> Wt_perm: [panel n/128][chunk k/8][row n%128][8] ----
__global__ __launch_bounds__(256) void wt_convert(
    const float* __restrict__ W, __hip_bfloat16* __restrict__ Wt) {
  int gidx = blockIdx.x * 256 + threadIdx.x;   // 512*128 granules
  int n = gidx >> 7;
  int c = gidx & 127;
  int k = c << 3;
  unsigned int oo[4];
#pragma unroll
  for (int h = 0; h < 4; ++h) {
    float a = W[(size_t)(k + 2 * h) * 512 + n];
    float b = W[(size_t)(k + 2 * h + 1) * 512 + n];
    oo[h] = (unsigned int)f2bf(a) | ((unsigned int)f2bf(b) << 16);
  }
  uint4 o = {oo[0], oo[1], oo[2], oo[3]};
  *(uint4*)(Wt + (size_t)(n >> 7) * 131072 + c * 1024 + (n & 127) * 8) = o;
}

// ---- 128x128 proj tile core; panels chunk-major, fully linear staging ----
__device__ __forceinline__ void gemm_tile_128p(
    const __hip_bfloat16* Ap, const __hip_bfloat16* Bp, int nkt,
    __hip_bfloat16* As, __hip_bfloat16* Bs, f32x4 acc[4][4], int tid) {
  int w = tid >> 6, lane = tid & 63;
  int wr = w >> 1, wc = w & 1;
  int g = lane >> 4, l16 = lane & 15;
  int wb = (tid & 0xC0) * 8;
  for (int t = 0; t < nkt; ++t) {
    gload_lds16(Ap + (size_t)t * 4096 + (size_t)tid * 8,         As + wb);
    gload_lds16(Ap + (size_t)t * 4096 + (size_t)(256 + tid) * 8, As + 2048 + wb);
    gload_lds16(Bp + (size_t)t * 4096 + (size_t)tid * 8,         Bs + wb);
    gload_lds16(Bp + (size_t)t * 4096 + (size_t)(256 + tid) * 8, Bs + 2048 + wb);
    __syncthreads();
    bf16x8 af[4], bfr[4];
#pragma unroll
    for (int mi = 0; mi < 4; ++mi)
      af[mi] = *(const bf16x8*)(As + g * 1024 + (wr * 64 + mi * 16 + l16) * 8);
#pragma unroll
    for (int ni = 0; ni < 4; ++ni)
      bfr[ni] = *(const bf16x8*)(Bs + g * 1024 + (wc * 64 + ni * 16 + l16) * 8);
#pragma unroll
    for (int mi = 0; mi < 4; ++mi)
#pragma unroll
      for (int ni = 0; ni < 4; ++ni)
        acc[mi][ni] = __builtin_amdgcn_mfma_f32_16x16x32_bf16(af[mi], bfr[ni], acc[mi][ni], 0, 0, 0);
    __syncthreads();
  }
}

// ---------------- projection GEMM: v = A @ Wt^T + b  (fp32 out) ----
__global__ __launch_bounds__(256) void proj_gemm(
    const __hip_bfloat16* __restrict__ Abig, const __hip_bfloat16* __restrict__ Wt,
    const float* __restrict__ bvec, float* __restrict__ v) {
  __shared__ __align__(16) __hip_bfloat16 As[4096], Bs[4096];
  int bn = blockIdx.x, bm = blockIdx.y;
  f32x4 acc[4][4];
#pragma unroll
  for (int i = 0; i < 4; ++i)
#pragma unroll
    for (int j = 0; j < 4; ++j) acc[i][j] = (f32x4){0.f, 0.f, 0.f, 0.f};
  int tid = threadIdx.x;
  gemm_tile_128p(Abig + (size_t)bm * 131072, Wt + (size_t)bn * 131072,
                 32, As, Bs, acc, tid);
  int w = tid >> 6, lane = tid & 63, wr = w >> 1, wc = w & 1, g = lane >> 4, l16 = lane & 15;
#pragma unroll
  for (int mi = 0; mi < 4; ++mi)
#pragma unroll
    for (int ni = 0; ni < 4; ++ni)
#pragma unroll
      for (int reg = 0; reg < 4; ++reg) {
        int grow = bm * 128 + wr * 64 + mi * 16 + g * 4 + reg;
        int gcol = bn * 128 + wc * 64 + ni * 16 + l16;
        v[(size_t)grow * 512 + gcol] = acc[mi][ni][reg] + bvec[gcol];
      }
}

// -- row L2-normalize; writes z_perm [panel r/256][chunk k/8][row r%256][8] --
__global__ __launch_bounds__(256) void normalize_rows(
    const float* __restrict__ v, __hip_bfloat16* __restrict__ z) {
  int r = blockIdx.x;
  int tid = threadIdx.x;
  const float* vr = v + (size_t)r * 512;
  float2 xv = *(const float2*)(vr + tid * 2);
  float s = xv.x * xv.x + xv.y * xv.y;
#pragma unroll
  for (int m = 1; m < 64; m <<= 1) s += __shfl_xor(s, m);
  __shared__ float ws4[4];
  int w = tid >> 6, lane = tid & 63;
  if (lane == 0) ws4[w] = s;
  __syncthreads();
  float tot = ws4[0] + ws4[1] + ws4[2] + ws4[3];
  float inv = 1.0f / fmaxf(sqrtf(tot), 1e-12f);
  unsigned int o = (unsigned int)f2bf(xv.x * inv) | ((unsigned int)f2bf(xv.y * inv) << 16);
  *(unsigned int*)(z + (size_t)(r >> 8) * 131072 + (tid >> 2) * 2048 +
                   (r & 255) * 8 + (tid & 3) * 2) = o;
}

// ==== fused symmetric sim: 128^2 tile, 4 waves, dbuf BK=32, 4 blocks/CU ====
// z_perm panels (256 rows, chunk-major). LDS buf per K-tile: A,B each
// [chunk 0..3][row 0..127][8] = 8 KB; double-buffered = 32 KB total.
// Supertile 12x12 ordering, XCD-chunked: 4656 pairs = 8 * 582 exactly.
__global__ __launch_bounds__(256, 4) void sim_fused_128(
    const __hip_bfloat16* __restrict__ z, float* __restrict__ partial,
    float* __restrict__ possim, float* __restrict__ selfsim) {
  __shared__ __align__(16) __hip_bfloat16 Ab[2][4096], Bb[2][4096];
  __shared__ float wsum[2][128];
  __shared__ float csum[2][128];

  // --- block -> (bi,bj), bi<=bj<96, supertile(12x12)-major, XCD-chunked ---
  int l = blockIdx.x;
  int q = (l & 7) * 582 + (l >> 3);
  int si = 0, sj = 0, jj = q;
  for (;;) {
    int cnt = (si == sj) ? 78 : 144;
    if (jj < cnt) break;
    jj -= cnt;
    ++sj;
    if (sj == 8) { ++si; sj = si; }
  }
  int bi, bj;
  if (si == sj) {
    int rr = 0;
    while (jj >= 12 - rr) { jj -= 12 - rr; ++rr; }
    bi = si * 12 + rr; bj = si * 12 + rr + jj;
  } else {
    bi = si * 12 + jj / 12; bj = sj * 12 + jj % 12;
  }

  // panel base: 256-row panel (bi>>1), half (bi&1) -> +128 rows = +1024 elems
  const __hip_bfloat16* zAp = z + (size_t)(bi >> 1) * 131072 + (bi & 1) * 1024;
  const __hip_bfloat16* zBp = z + (size_t)(bj >> 1) * 131072 + (bj & 1) * 1024;
  int tid = threadIdx.x;
  int lane = tid & 63;
  int w = tid >> 6, wr = w >> 1, wc = w & 1;
  int g = lane >> 4, l16 = lane & 15;
  // staging: granule (q*256+tid) -> chunk (q*256+tid)>>7, row &127
  const int soff0 = (tid >> 7) * 2048 + (tid & 127) * 8;  // src elems (chunk,row)
  const int ldst = w * 512;                               // wave-uniform dest base

  f32x4 acc[4][4];
#pragma unroll
  for (int i = 0; i < 4; ++i)
#pragma unroll
    for (int j = 0; j < 4; ++j) acc[i][j] = (f32x4){0.f, 0.f, 0.f, 0.f};

#define STAGE(TT, An, Bn) do { \
    gload_lds16(zAp + (TT) * 8192 + soff0,        (An) + ldst); \
    gload_lds16(zAp + (TT) * 8192 + 4096 + soff0, (An) + 2048 + ldst); \
    gload_lds16(zBp + (TT) * 8192 + soff0,        (Bn) + ldst); \
    gload_lds16(zBp + (TT) * 8192 + 4096 + soff0, (Bn) + 2048 + ldst); \
  } while (0)

  // prologue: stage K-tile 0
  STAGE(0, Ab[0], Bb[0]);
  __syncthreads();

  for (int t = 0; t < 16; ++t) {
    const __hip_bfloat16* Ac = Ab[t & 1];
    const __hip_bfloat16* Bc = Bb[t & 1];
    if (t < 15) STAGE(t + 1, Ab[(t + 1) & 1], Bb[(t + 1) & 1]);
    bf16x8 af[4], bfr[4];
#pragma unroll
    for (int mi = 0; mi < 4; ++mi)
      af[mi] = *(const bf16x8*)(Ac + g * 1024 + (wr * 64 + mi * 16 + l16) * 8);
#pragma unroll
    for (int ni = 0; ni < 4; ++ni)
      bfr[ni] = *(const bf16x8*)(Bc + g * 1024 + (wc * 64 + ni * 16 + l16) * 8);
#pragma unroll
    for (int mi = 0; mi < 4; ++mi)
#pragma unroll
      for (int ni = 0; ni < 4; ++ni)
        acc[mi][ni] = __builtin_amdgcn_mfma_f32_16x16x32_bf16(af[mi], bfr[ni], acc[mi][ni], 0, 0, 0);
    __syncthreads();
  }
#undef STAGE

  // --- epilogue ---
  bool diag = (bi == bj);
  bool posT = (bj == bi + 48);
  if ((diag || posT) && (wr == wc)) {
#pragma unroll
    for (int mi = 0; mi < 4; ++mi)
#pragma unroll
      for (int reg = 0; reg < 4; ++reg)
        if (l16 == g * 4 + reg) {
          int rl = wr * 64 + mi * 16 + g * 4 + reg;
          float sv = acc[mi][mi][reg];
          if (diag) selfsim[bi * 128 + rl] = sv;
          else      possim[bi * 128 + rl] = sv;   // bi < 48 here
        }
  }
  // exp in place
#pragma unroll
  for (int mi = 0; mi < 4; ++mi)
#pragma unroll
    for (int ni = 0; ni < 4; ++ni)
#pragma unroll
      for (int reg = 0; reg < 4; ++reg)
        acc[mi][ni][reg] = exp2f(acc[mi][ni][reg] * EXP_SCALE);
  // row sums (rows of bi-tile): in-thread over ni, l16 shuffle reduce
  float rs[4][4];
#pragma unroll
  for (int mi = 0; mi < 4; ++mi)
#pragma unroll
    for (int reg = 0; reg < 4; ++reg)
      rs[mi][reg] = acc[mi][0][reg] + acc[mi][1][reg] + acc[mi][2][reg] + acc[mi][3][reg];
#pragma unroll
  for (int m = 1; m < 16; m <<= 1)
#pragma unroll
    for (int mi = 0; mi < 4; ++mi)
#pragma unroll
      for (int reg = 0; reg < 4; ++reg)
        rs[mi][reg] += __shfl_xor(rs[mi][reg], m);
  if (l16 == 0) {
#pragma unroll
    for (int mi = 0; mi < 4; ++mi)
#pragma unroll
      for (int reg = 0; reg < 4; ++reg)
        wsum[wc][wr * 64 + mi * 16 + g * 4 + reg] = rs[mi][reg];
  }
  // col sums (rows of bj-tile): in-thread over mi,reg, g shuffle reduce
  float cs[4];
#pragma unroll
  for (int ni = 0; ni < 4; ++ni) {
    float s = 0.f;
#pragma unroll
    for (int mi = 0; mi < 4; ++mi)
#pragma unroll
      for (int reg = 0; reg < 4; ++reg) s += acc[mi][ni][reg];
    s += __shfl_xor(s, 16);
    s += __shfl_xor(s, 32);
    cs[ni] = s;
  }
  if (g == 0) {
#pragma unroll
    for (int ni = 0; ni < 4; ++ni)
      csum[wr][wc * 64 + ni * 16 + l16] = cs[ni];
  }
  __syncthreads();
  if (tid < 128) {
    partial[(size_t)bj * NROWS + bi * 128 + tid] = wsum[0][tid] + wsum[1][tid];
    if (!diag)
      partial[(size_t)bi * NROWS + bj * 128 + tid] = csum[0][tid] + csum[1][tid];
  }
}

// ---------------- per-row term ----------------
__global__ __launch_bounds__(256) void finalize_terms(
    const float* __restrict__ partial, const float* __restrict__ possim,
    const float* __restrict__ selfsim, float* __restrict__ terms) {
  int i = blockIdx.x * 256 + threadIdx.x;
  float s = 0.f;
  for (int bjt = 0; bjt < NTILE; ++bjt) s += partial[(size_t)bjt * NROWS + i];
  float denom = s - exp2f(selfsim[i] * EXP_SCALE);
  float pos = possim[(i < HALF) ? i : (i - HALF)];
  terms[i] = -2.0f * pos + logf(denom);
}

// ---------------- deterministic single-block sum ----------------
__global__ __launch_bounds__(256) void finalize_sum(
    const float* __restrict__ terms, float* __restrict__ out) {
  int tid = threadIdx.x;
  float s = 0.f;
  for (int i = tid; i < NROWS; i += 256) s += terms[i];
#pragma unroll
  for (int m = 1; m < 64; m <<= 1) s += __shfl_xor(s, m);
  __shared__ float ws4[4];
  int w = tid >> 6, lane = tid & 63;
  if (lane == 0) ws4[w] = s;
  __syncthreads();
  if (tid == 0) out[0] = (ws4[0] + ws4[1] + ws4[2] + ws4[3]) / 12288.0f;
}

extern "C" void kernel_launch(void* const* d_in, const int* in_sizes, int n_in,
                              void* d_out, int out_size, void* d_ws, size_t ws_size,
                              hipStream_t stream) {
  const float* f_seq = (const float*)d_in[0];
  const float* f_spa = (const float*)d_in[1];
  const float* W     = (const float*)d_in[2];
  const float* b     = (const float*)d_in[3];
  char* ws = (char*)d_ws;
  __hip_bfloat16* Abig = (__hip_bfloat16*)ws;                // 25165824 B
  __hip_bfloat16* Wt   = (__hip_bfloat16*)(ws + 25165824);   // 1048576 B
  float* v             = (float*)(ws + 26214400);            // 25165824 B
  __hip_bfloat16* z    = (__hip_bfloat16*)ws;                // alias over dead Abig
  float* partial       = (float*)(ws + 12582912);            // 96*12288*4 = 4718592
  float* possim        = (float*)(ws + 17301504);            // 6144*4
  float* selfsim       = (float*)(ws + 17326080);            // 12288*4
  float* terms         = (float*)(ws + 17375232);            // 12288*4
  float* out           = (float*)d_out;

  gather_convert<<<dim3(6144), dim3(256), 0, stream>>>(f_seq, f_spa, Abig);
  wt_convert<<<dim3(256), dim3(256), 0, stream>>>(W, Wt);
  proj_gemm<<<dim3(4, 96), dim3(256), 0, stream>>>(Abig, Wt, b, v);
  normalize_rows<<<dim3(12288), dim3(256), 0, stream>>>(v, z);
  sim_fused_128<<<dim3(NPAIR), dim3(256), 0, stream>>>(z, partial, possim, selfsim);
  finalize_terms<<<dim3(48), dim3(256), 0, stream>>>(partial, possim, selfsim, terms);
  finalize_sum<<<dim3(1), dim3(256), 0, stream>>>(terms, out);
}

// Round 6
// 158.780 us; speedup vs baseline: 1.7907x; 1.1060x over previous
//
#include <hip/hip_runtime.h>
#include <hip/hip_bf16.h>
#include <cstdint>
#include <cstddef>

#define B_DIM 2048
#define D_DIM 512
#define NROWS 12288        // 6B rows of z
#define HALF  6144         // 3B
#define NTILE 96           // 128-row tiles per dim
#define NPAIR 4656         // 96*97/2 upper-tri tiles
#define EXP_SCALE 2.8853900817779268f   // log2(e)/TEMP, TEMP=0.5

typedef __attribute__((ext_vector_type(8))) __bf16 bf16x8;
typedef __attribute__((ext_vector_type(4))) float f32x4;
typedef __attribute__((ext_vector_type(8))) int i32x8;

__device__ __forceinline__ unsigned short f2bf(float x) {
  __hip_bfloat16 h = __float2bfloat16(x);
  return *reinterpret_cast<unsigned short*>(&h);
}

__device__ __forceinline__ void gload_lds16(const void* g, void* l) {
  __builtin_amdgcn_global_load_lds(
      (const __attribute__((address_space(1))) unsigned int*)g,
      (__attribute__((address_space(3))) unsigned int*)l,
      16, 0, 0);
}

// ---- gather f -> Abig_perm bf16: [panel r/128][chunk k/8][row r%128][8] ----
__global__ __launch_bounds__(256) void gather_convert(
    const float* __restrict__ f_seq, const float* __restrict__ f_spa,
    __hip_bfloat16* __restrict__ Abig) {
  int gidx = blockIdx.x * 256 + threadIdx.x;   // 12288*128 granules
  int r = gidx >> 7;
  int c = gidx & 127;
  int k = c << 3;
  const float* f = (r < HALF) ? f_spa : f_seq;
  int rr = (r < HALF) ? r : r - HALF;
  int p = rr >> 11;
  int i = rr & 2047;
  int sel = (p == 2) ? 3 : p;
  const float* src;
  if (k < D_DIM) src = f + ((size_t)i * 4 + sel) * D_DIM + k;
  else           src = f + ((size_t)i * 4 + 2) * D_DIM + (k - D_DIM);
  float4 x0 = *(const float4*)src;
  float4 x1 = *(const float4*)(src + 4);
  uint4 o;
  o.x = (unsigned int)f2bf(x0.x) | ((unsigned int)f2bf(x0.y) << 16);
  o.y = (unsigned int)f2bf(x0.z) | ((unsigned int)f2bf(x0.w) << 16);
  o.z = (unsigned int)f2bf(x1.x) | ((unsigned int)f2bf(x1.y) << 16);
  o.w = (unsigned int)f2bf(x1.z) | ((unsigned int)f2bf(x1.w) << 16);
  *(uint4*)(Abig + (size_t)(r >> 7) * 131072 + c * 1024 + (r & 127) * 8) = o;
}

// ---- W [1024x512] -> Wt_perm: [panel n/128][chunk k/8][row n%128][8] ----
__global__ __launch_bounds__(256) void wt_convert(
    const float* __restrict__ W, __hip_bfloat16* __restrict__ Wt) {
  int gidx = blockIdx.x * 256 + threadIdx.x;   // 512*128 granules
  int n = gidx >> 7;
  int c = gidx & 127;
  int k = c << 3;
  unsigned int oo[4];
#pragma unroll
  for (int h = 0; h < 4; ++h) {
    float a = W[(size_t)(k + 2 * h) * 512 + n];
    float b = W[(size_t)(k + 2 * h + 1) * 512 + n];
    oo[h] = (unsigned int)f2bf(a) | ((unsigned int)f2bf(b) << 16);
  }
  uint4 o = {oo[0], oo[1], oo[2], oo[3]};
  *(uint4*)(Wt + (size_t)(n >> 7) * 131072 + c * 1024 + (n & 127) * 8) = o;
}

// ---- 128x128 proj tile core; panels chunk-major, fully linear staging ----
__device__ __forceinline__ void gemm_tile_128p(
    const __hip_bfloat16* Ap, const __hip_bfloat16* Bp, int nkt,
    __hip_bfloat16* As, __hip_bfloat16* Bs, f32x4 acc[4][4], int tid) {
  int w = tid >> 6, lane = tid & 63;
  int wr = w >> 1, wc = w & 1;
  int g = lane >> 4, l16 = lane & 15;
  int wb = (tid & 0xC0) * 8;
  for (int t = 0; t < nkt; ++t) {
    gload_lds16(Ap + (size_t)t * 4096 + (size_t)tid * 8,         As + wb);
    gload_lds16(Ap + (size_t)t * 4096 + (size_t)(256 + tid) * 8, As + 2048 + wb);
    gload_lds16(Bp + (size_t)t * 4096 + (size_t)tid * 8,         Bs + wb);
    gload_lds16(Bp + (size_t)t * 4096 + (size_t)(256 + tid) * 8, Bs + 2048 + wb);
    __syncthreads();
    bf16x8 af[4], bfr[4];
#pragma unroll
    for (int mi = 0; mi < 4; ++mi)
      af[mi] = *(const bf16x8*)(As + g * 1024 + (wr * 64 + mi * 16 + l16) * 8);
#pragma unroll
    for (int ni = 0; ni < 4; ++ni)
      bfr[ni] = *(const bf16x8*)(Bs + g * 1024 + (wc * 64 + ni * 16 + l16) * 8);
#pragma unroll
    for (int mi = 0; mi < 4; ++mi)
#pragma unroll
      for (int ni = 0; ni < 4; ++ni)
        acc[mi][ni] = __builtin_amdgcn_mfma_f32_16x16x32_bf16(af[mi], bfr[ni], acc[mi][ni], 0, 0, 0);
    __syncthreads();
  }
}

// ---------------- projection GEMM: v = A @ Wt^T + b  (fp32 out) ----
__global__ __launch_bounds__(256) void proj_gemm(
    const __hip_bfloat16* __restrict__ Abig, const __hip_bfloat16* __restrict__ Wt,
    const float* __restrict__ bvec, float* __restrict__ v) {
  __shared__ __align__(16) __hip_bfloat16 As[4096], Bs[4096];
  int bn = blockIdx.x, bm = blockIdx.y;
  f32x4 acc[4][4];
#pragma unroll
  for (int i = 0; i < 4; ++i)
#pragma unroll
    for (int j = 0; j < 4; ++j) acc[i][j] = (f32x4){0.f, 0.f, 0.f, 0.f};
  int tid = threadIdx.x;
  gemm_tile_128p(Abig + (size_t)bm * 131072, Wt + (size_t)bn * 131072,
                 32, As, Bs, acc, tid);
  int w = tid >> 6, lane = tid & 63, wr = w >> 1, wc = w & 1, g = lane >> 4, l16 = lane & 15;
#pragma unroll
  for (int mi = 0; mi < 4; ++mi)
#pragma unroll
    for (int ni = 0; ni < 4; ++ni)
#pragma unroll
      for (int reg = 0; reg < 4; ++reg) {
        int grow = bm * 128 + wr * 64 + mi * 16 + g * 4 + reg;
        int gcol = bn * 128 + wc * 64 + ni * 16 + l16;
        v[(size_t)grow * 512 + gcol] = acc[mi][ni][reg] + bvec[gcol];
      }
}

// -- row L2-normalize -> z fp8(e4m3), global layout = per-tile LDS image --
// z: [panel r/128][ktile k/128][granule][16B], granule byte offset within
// 16KB tile = rowgrp*2048 + h*1024 + kc*256 + (r&15)*16,
// rowgrp=(r>>4)&7, kc=(k%128)/32, h=((k%32)>>4).
__global__ __launch_bounds__(256) void normalize_rows(
    const float* __restrict__ v, unsigned char* __restrict__ z) {
  int r = blockIdx.x;
  int tid = threadIdx.x;
  const float* vr = v + (size_t)r * 512;
  float2 xv = *(const float2*)(vr + tid * 2);
  float s = xv.x * xv.x + xv.y * xv.y;
#pragma unroll
  for (int m = 1; m < 64; m <<= 1) s += __shfl_xor(s, m);
  __shared__ float ws4[4];
  __shared__ float zf[512];
  int w = tid >> 6, lane = tid & 63;
  if (lane == 0) ws4[w] = s;
  __syncthreads();
  float tot = ws4[0] + ws4[1] + ws4[2] + ws4[3];
  float inv = 1.0f / fmaxf(sqrtf(tot), 1e-12f);
  zf[2 * tid]     = xv.x * inv;
  zf[2 * tid + 1] = xv.y * inv;
  __syncthreads();
  if (tid < 32) {
    int t = tid >> 3, kc = (tid >> 1) & 3, h = tid & 1;
    int k0 = t * 128 + kc * 32 + h * 16;
    unsigned int d[4];
#pragma unroll
    for (int q = 0; q < 4; ++q) {
      int pk = __builtin_amdgcn_cvt_pk_fp8_f32(zf[k0 + 4 * q],     zf[k0 + 4 * q + 1], 0, 0);
      pk     = __builtin_amdgcn_cvt_pk_fp8_f32(zf[k0 + 4 * q + 2], zf[k0 + 4 * q + 3], pk, 1);
      d[q] = (unsigned int)pk;
    }
    uint4 o = {d[0], d[1], d[2], d[3]};
    size_t off = (size_t)(r >> 7) * 65536 + (size_t)t * 16384 +
                 (size_t)((((r >> 4) & 7) * 2 + h) * 1024 + kc * 256 + (r & 15) * 16);
    *(uint4*)(z + off) = o;
  }
}

// ==== fused symmetric sim, fp8 MX: 128^2 tile, BK=128, dbuf, 2 blk/CU ====
// LDS: A0@0 B0@16K A1@32K B1@48K (16KB each, dbuf) = 64KB dynamic.
// Per-lane A/B frag: row=l&15 (per 16-row group), k=(l>>4)*32+0..31 (32B).
// ds_read: per instr 64 lanes read 1KB contiguous -> conflict-free.
#define SIMF_SMEM 65536
__global__ __launch_bounds__(256, 2) void sim_fused_fp8(
    const unsigned char* __restrict__ z, float* __restrict__ partial,
    float* __restrict__ possim, float* __restrict__ selfsim) {
  extern __shared__ __align__(16) char smem[];

  // --- block -> (bi,bj), bi<=bj<96, supertile(12x12)-major, XCD-chunked ---
  int l = blockIdx.x;
  int q = (l & 7) * 582 + (l >> 3);
  int si = 0, sj = 0, jj = q;
  for (;;) {
    int cnt = (si == sj) ? 78 : 144;
    if (jj < cnt) break;
    jj -= cnt;
    ++sj;
    if (sj == 8) { ++si; sj = si; }
  }
  int bi, bj;
  if (si == sj) {
    int rr = 0;
    while (jj >= 12 - rr) { jj -= 12 - rr; ++rr; }
    bi = si * 12 + rr; bj = si * 12 + rr + jj;
  } else {
    bi = si * 12 + jj / 12; bj = sj * 12 + jj % 12;
  }

  const unsigned char* zAp = z + (size_t)bi * 65536;
  const unsigned char* zBp = z + (size_t)bj * 65536;
  int tid = threadIdx.x;
  int lane = tid & 63;
  int w = tid >> 6, wr = w >> 1, wc = w & 1;
  int g = lane >> 4, l16 = lane & 15;
  const int wdst = (tid & 0xC0) * 16;     // wave-uniform LDS dest base (bytes)

  f32x4 acc[4][4];
#pragma unroll
  for (int i = 0; i < 4; ++i)
#pragma unroll
    for (int j = 0; j < 4; ++j) acc[i][j] = (f32x4){0.f, 0.f, 0.f, 0.f};

#define STAGE(TT, Abuf, Bbuf) do { \
    size_t tko = (size_t)(TT) * 16384 + (size_t)tid * 16; \
    _Pragma("unroll") \
    for (int r = 0; r < 4; ++r) { \
      gload_lds16(zAp + tko + r * 4096, (Abuf) + r * 4096 + wdst); \
      gload_lds16(zBp + tko + r * 4096, (Bbuf) + r * 4096 + wdst); \
    } \
  } while (0)

  // prologue: stage K-tile 0
  STAGE(0, smem, smem + 16384);
  __syncthreads();

  for (int t = 0; t < 4; ++t) {
    const char* Acur = smem + (t & 1) * 32768;
    const char* Bcur = smem + 16384 + (t & 1) * 32768;
    if (t < 3) STAGE(t + 1, smem + ((t + 1) & 1) * 32768,
                            smem + 16384 + ((t + 1) & 1) * 32768);
    i32x8 aF[4], bF[4];
#pragma unroll
    for (int mi = 0; mi < 4; ++mi) {
      const char* pa = Acur + (wr * 4 + mi) * 2048 + g * 256 + l16 * 16;
      uint4 h0 = *(const uint4*)pa;
      uint4 h1 = *(const uint4*)(pa + 1024);
      aF[mi] = (i32x8){(int)h0.x, (int)h0.y, (int)h0.z, (int)h0.w,
                       (int)h1.x, (int)h1.y, (int)h1.z, (int)h1.w};
    }
#pragma unroll
    for (int ni = 0; ni < 4; ++ni) {
      const char* pb = Bcur + (wc * 4 + ni) * 2048 + g * 256 + l16 * 16;
      uint4 h0 = *(const uint4*)pb;
      uint4 h1 = *(const uint4*)(pb + 1024);
      bF[ni] = (i32x8){(int)h0.x, (int)h0.y, (int)h0.z, (int)h0.w,
                       (int)h1.x, (int)h1.y, (int)h1.z, (int)h1.w};
    }
#pragma unroll
    for (int mi = 0; mi < 4; ++mi)
#pragma unroll
      for (int ni = 0; ni < 4; ++ni)
        acc[mi][ni] = __builtin_amdgcn_mfma_scale_f32_16x16x128_f8f6f4(
            aF[mi], bF[ni], acc[mi][ni], 0, 0,
            0, 0x7F7F7F7F, 0, 0x7F7F7F7F);
    __syncthreads();
  }
#undef STAGE

  // --- epilogue (identical to verified bf16 version; buffers alias smem) ---
  float* wsum = (float*)smem;          // [2][128]
  float* csum = (float*)(smem + 2048); // [2][128]
  bool diag = (bi == bj);
  bool posT = (bj == bi + 48);
  if ((diag || posT) && (wr == wc)) {
#pragma unroll
    for (int mi = 0; mi < 4; ++mi)
#pragma unroll
      for (int reg = 0; reg < 4; ++reg)
        if (l16 == g * 4 + reg) {
          int rl = wr * 64 + mi * 16 + g * 4 + reg;
          float sv = acc[mi][mi][reg];
          if (diag) selfsim[bi * 128 + rl] = sv;
          else      possim[bi * 128 + rl] = sv;   // bi < 48 here
        }
  }
  // exp in place
#pragma unroll
  for (int mi = 0; mi < 4; ++mi)
#pragma unroll
    for (int ni = 0; ni < 4; ++ni)
#pragma unroll
      for (int reg = 0; reg < 4; ++reg)
        acc[mi][ni][reg] = exp2f(acc[mi][ni][reg] * EXP_SCALE);
  // row sums (bi rows): in-thread over ni, l16 shuffle reduce
  float rs[4][4];
#pragma unroll
  for (int mi = 0; mi < 4; ++mi)
#pragma unroll
    for (int reg = 0; reg < 4; ++reg)
      rs[mi][reg] = acc[mi][0][reg] + acc[mi][1][reg] + acc[mi][2][reg] + acc[mi][3][reg];
#pragma unroll
  for (int m = 1; m < 16; m <<= 1)
#pragma unroll
    for (int mi = 0; mi < 4; ++mi)
#pragma unroll
      for (int reg = 0; reg < 4; ++reg)
        rs[mi][reg] += __shfl_xor(rs[mi][reg], m);
  if (l16 == 0) {
#pragma unroll
    for (int mi = 0; mi < 4; ++mi)
#pragma unroll
      for (int reg = 0; reg < 4; ++reg)
        wsum[wc * 128 + wr * 64 + mi * 16 + g * 4 + reg] = rs[mi][reg];
  }
  // col sums (bj rows): in-thread over mi,reg, g shuffle reduce
  float cs[4];
#pragma unroll
  for (int ni = 0; ni < 4; ++ni) {
    float s = 0.f;
#pragma unroll
    for (int mi = 0; mi < 4; ++mi)
#pragma unroll
      for (int reg = 0; reg < 4; ++reg) s += acc[mi][ni][reg];
    s += __shfl_xor(s, 16);
    s += __shfl_xor(s, 32);
    cs[ni] = s;
  }
  if (g == 0) {
#pragma unroll
    for (int ni = 0; ni < 4; ++ni)
      csum[wr * 128 + wc * 64 + ni * 16 + l16] = cs[ni];
  }
  __syncthreads();
  if (tid < 128) {
    partial[(size_t)bj * NROWS + bi * 128 + tid] = wsum[tid] + wsum[128 + tid];
    if (!diag)
      partial[(size_t)bi * NROWS + bj * 128 + tid] = csum[tid] + csum[128 + tid];
  }
}

// ---------------- per-row term ----------------
__global__ __launch_bounds__(256) void finalize_terms(
    const float* __restrict__ partial, const float* __restrict__ possim,
    const float* __restrict__ selfsim, float* __restrict__ terms) {
  int i = blockIdx.x * 256 + threadIdx.x;
  float s = 0.f;
  for (int bjt = 0; bjt < NTILE; ++bjt) s += partial[(size_t)bjt * NROWS + i];
  float denom = s - exp2f(selfsim[i] * EXP_SCALE);
  float pos = possim[(i < HALF) ? i : (i - HALF)];
  terms[i] = -2.0f * pos + logf(denom);
}

// ---------------- deterministic single-block sum ----------------
__global__ __launch_bounds__(256) void finalize_sum(
    const float* __restrict__ terms, float* __restrict__ out) {
  int tid = threadIdx.x;
  float s = 0.f;
  for (int i = tid; i < NROWS; i += 256) s += terms[i];
#pragma unroll
  for (int m = 1; m < 64; m <<= 1) s += __shfl_xor(s, m);
  __shared__ float ws4[4];
  int w = tid >> 6, lane = tid & 63;
  if (lane == 0) ws4[w] = s;
  __syncthreads();
  if (tid == 0) out[0] = (ws4[0] + ws4[1] + ws4[2] + ws4[3]) / 12288.0f;
}

extern "C" void kernel_launch(void* const* d_in, const int* in_sizes, int n_in,
                              void* d_out, int out_size, void* d_ws, size_t ws_size,
                              hipStream_t stream) {
  const float* f_seq = (const float*)d_in[0];
  const float* f_spa = (const float*)d_in[1];
  const float* W     = (const float*)d_in[2];
  const float* b     = (const float*)d_in[3];
  char* ws = (char*)d_ws;
  __hip_bfloat16* Abig = (__hip_bfloat16*)ws;                // 25165824 B
  __hip_bfloat16* Wt   = (__hip_bfloat16*)(ws + 25165824);   // 1048576 B
  float* v             = (float*)(ws + 26214400);            // 25165824 B
  unsigned char* z     = (unsigned char*)ws;                 // fp8, 6291456 B (aliases dead Abig)
  float* partial       = (float*)(ws + 12582912);            // 96*12288*4 = 4718592
  float* possim        = (float*)(ws + 17301504);            // 6144*4
  float* selfsim       = (float*)(ws + 17326080);            // 12288*4
  float* terms         = (float*)(ws + 17375232);            // 12288*4
  float* out           = (float*)d_out;

  hipFuncSetAttribute((const void*)sim_fused_fp8,
                      hipFuncAttributeMaxDynamicSharedMemorySize, SIMF_SMEM);

  gather_convert<<<dim3(6144), dim3(256), 0, stream>>>(f_seq, f_spa, Abig);
  wt_convert<<<dim3(256), dim3(256), 0, stream>>>(W, Wt);
  proj_gemm<<<dim3(4, 96), dim3(256), 0, stream>>>(Abig, Wt, b, v);
  normalize_rows<<<dim3(12288), dim3(256), 0, stream>>>(v, z);
  sim_fused_fp8<<<dim3(NPAIR), dim3(256), SIMF_SMEM, stream>>>(z, partial, possim, selfsim);
  finalize_terms<<<dim3(48), dim3(256), 0, stream>>>(partial, possim, selfsim, terms);
  finalize_sum<<<dim3(1), dim3(256), 0, stream>>>(terms, out);
}

// Round 7
// 154.775 us; speedup vs baseline: 1.8371x; 1.0259x over previous
//
#include <hip/hip_runtime.h>
#include <hip/hip_bf16.h>
#include <cstdint>
#include <cstddef>

#define B_DIM 2048
#define D_DIM 512
#define NROWS 12288        // 6B rows of z
#define HALF  6144         // 3B
#define NTILE 96           // 128-row tiles per dim
#define NPAIR 4656         // 96*97/2 upper-tri tiles
#define EXP_SCALE 2.8853900817779268f   // log2(e)/TEMP, TEMP=0.5

typedef __attribute__((ext_vector_type(8))) __bf16 bf16x8;
typedef __attribute__((ext_vector_type(4))) float f32x4;
typedef __attribute__((ext_vector_type(8))) int i32x8;

__device__ __forceinline__ unsigned short f2bf(float x) {
  __hip_bfloat16 h = __float2bfloat16(x);
  return *reinterpret_cast<unsigned short*>(&h);
}

__device__ __forceinline__ void gload_lds16(const void* g, void* l) {
  __builtin_amdgcn_global_load_lds(
      (const __attribute__((address_space(1))) unsigned int*)g,
      (__attribute__((address_space(3))) unsigned int*)l,
      16, 0, 0);
}

// ---- gather f -> Abig_perm bf16: [panel r/128][chunk k/8][row r%128][8] ----
__global__ __launch_bounds__(256) void gather_convert(
    const float* __restrict__ f_seq, const float* __restrict__ f_spa,
    __hip_bfloat16* __restrict__ Abig) {
  int gidx = blockIdx.x * 256 + threadIdx.x;   // 12288*128 granules
  int r = gidx >> 7;
  int c = gidx & 127;
  int k = c << 3;
  const float* f = (r < HALF) ? f_spa : f_seq;
  int rr = (r < HALF) ? r : r - HALF;
  int p = rr >> 11;
  int i = rr & 2047;
  int sel = (p == 2) ? 3 : p;
  const float* src;
  if (k < D_DIM) src = f + ((size_t)i * 4 + sel) * D_DIM + k;
  else           src = f + ((size_t)i * 4 + 2) * D_DIM + (k - D_DIM);
  float4 x0 = *(const float4*)src;
  float4 x1 = *(const float4*)(src + 4);
  uint4 o;
  o.x = (unsigned int)f2bf(x0.x) | ((unsigned int)f2bf(x0.y) << 16);
  o.y = (unsigned int)f2bf(x0.z) | ((unsigned int)f2bf(x0.w) << 16);
  o.z = (unsigned int)f2bf(x1.x) | ((unsigned int)f2bf(x1.y) << 16);
  o.w = (unsigned int)f2bf(x1.z) | ((unsigned int)f2bf(x1.w) << 16);
  *(uint4*)(Abig + (size_t)(r >> 7) * 131072 + c * 1024 + (r & 127) * 8) = o;
}

// ---- W [1024x512] -> Wt_perm: [panel n/128][chunk k/8][row n%128][8] ----
__global__ __launch_bounds__(256) void wt_convert(
    const float* __restrict__ W, __hip_bfloat16* __restrict__ Wt) {
  int gidx = blockIdx.x * 256 + threadIdx.x;   // 512*128 granules
  int n = gidx >> 7;
  int c = gidx & 127;
  int k = c << 3;
  unsigned int oo[4];
#pragma unroll
  for (int h = 0; h < 4; ++h) {
    float a = W[(size_t)(k + 2 * h) * 512 + n];
    float b = W[(size_t)(k + 2 * h + 1) * 512 + n];
    oo[h] = (unsigned int)f2bf(a) | ((unsigned int)f2bf(b) << 16);
  }
  uint4 o = {oo[0], oo[1], oo[2], oo[3]};
  *(uint4*)(Wt + (size_t)(n >> 7) * 131072 + c * 1024 + (n & 127) * 8) = o;
}

// ---- 128x128 proj tile core; panels chunk-major, fully linear staging ----
__device__ __forceinline__ void gemm_tile_128p(
    const __hip_bfloat16* Ap, const __hip_bfloat16* Bp, int nkt,
    __hip_bfloat16* As, __hip_bfloat16* Bs, f32x4 acc[4][4], int tid) {
  int w = tid >> 6, lane = tid & 63;
  int wr = w >> 1, wc = w & 1;
  int g = lane >> 4, l16 = lane & 15;
  int wb = (tid & 0xC0) * 8;
  for (int t = 0; t < nkt; ++t) {
    gload_lds16(Ap + (size_t)t * 4096 + (size_t)tid * 8,         As + wb);
    gload_lds16(Ap + (size_t)t * 4096 + (size_t)(256 + tid) * 8, As + 2048 + wb);
    gload_lds16(Bp + (size_t)t * 4096 + (size_t)tid * 8,         Bs + wb);
    gload_lds16(Bp + (size_t)t * 4096 + (size_t)(256 + tid) * 8, Bs + 2048 + wb);
    __syncthreads();
    bf16x8 af[4], bfr[4];
#pragma unroll
    for (int mi = 0; mi < 4; ++mi)
      af[mi] = *(const bf16x8*)(As + g * 1024 + (wr * 64 + mi * 16 + l16) * 8);
#pragma unroll
    for (int ni = 0; ni < 4; ++ni)
      bfr[ni] = *(const bf16x8*)(Bs + g * 1024 + (wc * 64 + ni * 16 + l16) * 8);
#pragma unroll
    for (int mi = 0; mi < 4; ++mi)
#pragma unroll
      for (int ni = 0; ni < 4; ++ni)
        acc[mi][ni] = __builtin_amdgcn_mfma_f32_16x16x32_bf16(af[mi], bfr[ni], acc[mi][ni], 0, 0, 0);
    __syncthreads();
  }
}

// ---------------- projection GEMM: v = A @ Wt^T + b  (fp32 out) ----
__global__ __launch_bounds__(256) void proj_gemm(
    const __hip_bfloat16* __restrict__ Abig, const __hip_bfloat16* __restrict__ Wt,
    const float* __restrict__ bvec, float* __restrict__ v) {
  __shared__ __align__(16) __hip_bfloat16 As[4096], Bs[4096];
  int bn = blockIdx.x, bm = blockIdx.y;
  f32x4 acc[4][4];
#pragma unroll
  for (int i = 0; i < 4; ++i)
#pragma unroll
    for (int j = 0; j < 4; ++j) acc[i][j] = (f32x4){0.f, 0.f, 0.f, 0.f};
  int tid = threadIdx.x;
  gemm_tile_128p(Abig + (size_t)bm * 131072, Wt + (size_t)bn * 131072,
                 32, As, Bs, acc, tid);
  int w = tid >> 6, lane = tid & 63, wr = w >> 1, wc = w & 1, g = lane >> 4, l16 = lane & 15;
#pragma unroll
  for (int mi = 0; mi < 4; ++mi)
#pragma unroll
    for (int ni = 0; ni < 4; ++ni)
#pragma unroll
      for (int reg = 0; reg < 4; ++reg) {
        int grow = bm * 128 + wr * 64 + mi * 16 + g * 4 + reg;
        int gcol = bn * 128 + wc * 64 + ni * 16 + l16;
        v[(size_t)grow * 512 + gcol] = acc[mi][ni][reg] + bvec[gcol];
      }
}

// -- row L2-normalize -> z fp8(e4m3), global layout = per-tile fragment image --
// z: [panel r/128][ktile k/128][granule][16B], granule byte offset within
// 16KB tile = rowgrp*2048 + h*1024 + kc*256 + (r&15)*16,
// rowgrp=(r>>4)&7, kc=(k%128)/32, h=((k%32)>>4).
__global__ __launch_bounds__(256) void normalize_rows(
    const float* __restrict__ v, unsigned char* __restrict__ z) {
  int r = blockIdx.x;
  int tid = threadIdx.x;
  const float* vr = v + (size_t)r * 512;
  float2 xv = *(const float2*)(vr + tid * 2);
  float s = xv.x * xv.x + xv.y * xv.y;
#pragma unroll
  for (int m = 1; m < 64; m <<= 1) s += __shfl_xor(s, m);
  __shared__ float ws4[4];
  __shared__ float zf[512];
  int w = tid >> 6, lane = tid & 63;
  if (lane == 0) ws4[w] = s;
  __syncthreads();
  float tot = ws4[0] + ws4[1] + ws4[2] + ws4[3];
  float inv = 1.0f / fmaxf(sqrtf(tot), 1e-12f);
  zf[2 * tid]     = xv.x * inv;
  zf[2 * tid + 1] = xv.y * inv;
  __syncthreads();
  if (tid < 32) {
    int t = tid >> 3, kc = (tid >> 1) & 3, h = tid & 1;
    int k0 = t * 128 + kc * 32 + h * 16;
    unsigned int d[4];
#pragma unroll
    for (int q = 0; q < 4; ++q) {
      int pk = __builtin_amdgcn_cvt_pk_fp8_f32(zf[k0 + 4 * q],     zf[k0 + 4 * q + 1], 0, 0);
      pk     = __builtin_amdgcn_cvt_pk_fp8_f32(zf[k0 + 4 * q + 2], zf[k0 + 4 * q + 3], pk, 1);
      d[q] = (unsigned int)pk;
    }
    uint4 o = {d[0], d[1], d[2], d[3]};
    size_t off = (size_t)(r >> 7) * 65536 + (size_t)t * 16384 +
                 (size_t)((((r >> 4) & 7) * 2 + h) * 1024 + kc * 256 + (r & 15) * 16);
    *(uint4*)(z + off) = o;
  }
}

// ==== fused symmetric sim, fp8 MX, REGISTER-DIRECT fragments ====
// No LDS staging, no main-loop barriers: z's global layout IS the fragment
// image; each fragment load = one coalesced 1KB wave read (L1/L2-resident:
// per-block tile 16KB, supertile working set ~768KB). Latency hidden by
// 16 waves/CU (4 blocks) + unrolled barrier-free loop.
__global__ __launch_bounds__(256, 4) void sim_fused_fp8(
    const unsigned char* __restrict__ z, float* __restrict__ partial,
    float* __restrict__ possim, float* __restrict__ selfsim) {
  __shared__ float wsum[2][128];
  __shared__ float csum[2][128];

  // --- block -> (bi,bj), bi<=bj<96, supertile(12x12)-major, XCD-chunked ---
  int l = blockIdx.x;
  int q = (l & 7) * 582 + (l >> 3);
  int si = 0, sj = 0, jj = q;
  for (;;) {
    int cnt = (si == sj) ? 78 : 144;
    if (jj < cnt) break;
    jj -= cnt;
    ++sj;
    if (sj == 8) { ++si; sj = si; }
  }
  int bi, bj;
  if (si == sj) {
    int rr = 0;
    while (jj >= 12 - rr) { jj -= 12 - rr; ++rr; }
    bi = si * 12 + rr; bj = si * 12 + rr + jj;
  } else {
    bi = si * 12 + jj / 12; bj = sj * 12 + jj % 12;
  }

  int tid = threadIdx.x;
  int lane = tid & 63;
  int w = tid >> 6, wr = w >> 1, wc = w & 1;
  int g = lane >> 4, l16 = lane & 15;

  // per-lane fragment base addresses (bytes)
  const unsigned char* pA = z + (size_t)bi * 65536 + (size_t)(wr * 4) * 2048 + g * 256 + l16 * 16;
  const unsigned char* pB = z + (size_t)bj * 65536 + (size_t)(wc * 4) * 2048 + g * 256 + l16 * 16;

  f32x4 acc[4][4];
#pragma unroll
  for (int i = 0; i < 4; ++i)
#pragma unroll
    for (int j = 0; j < 4; ++j) acc[i][j] = (f32x4){0.f, 0.f, 0.f, 0.f};

#pragma unroll
  for (int t = 0; t < 4; ++t) {
    uint4 a0[4], a1[4], b0[4], b1[4];
#pragma unroll
    for (int mi = 0; mi < 4; ++mi) {
      a0[mi] = *(const uint4*)(pA + t * 16384 + mi * 2048);
      a1[mi] = *(const uint4*)(pA + t * 16384 + mi * 2048 + 1024);
    }
#pragma unroll
    for (int ni = 0; ni < 4; ++ni) {
      b0[ni] = *(const uint4*)(pB + t * 16384 + ni * 2048);
      b1[ni] = *(const uint4*)(pB + t * 16384 + ni * 2048 + 1024);
    }
#pragma unroll
    for (int mi = 0; mi < 4; ++mi) {
      i32x8 aF = (i32x8){(int)a0[mi].x, (int)a0[mi].y, (int)a0[mi].z, (int)a0[mi].w,
                         (int)a1[mi].x, (int)a1[mi].y, (int)a1[mi].z, (int)a1[mi].w};
#pragma unroll
      for (int ni = 0; ni < 4; ++ni) {
        i32x8 bF = (i32x8){(int)b0[ni].x, (int)b0[ni].y, (int)b0[ni].z, (int)b0[ni].w,
                           (int)b1[ni].x, (int)b1[ni].y, (int)b1[ni].z, (int)b1[ni].w};
        acc[mi][ni] = __builtin_amdgcn_mfma_scale_f32_16x16x128_f8f6f4(
            aF, bF, acc[mi][ni], 0, 0,
            0, 0x7F7F7F7F, 0, 0x7F7F7F7F);
      }
    }
  }

  // --- epilogue (identical to verified R5/R6 version) ---
  bool diag = (bi == bj);
  bool posT = (bj == bi + 48);
  if ((diag || posT) && (wr == wc)) {
#pragma unroll
    for (int mi = 0; mi < 4; ++mi)
#pragma unroll
      for (int reg = 0; reg < 4; ++reg)
        if (l16 == g * 4 + reg) {
          int rl = wr * 64 + mi * 16 + g * 4 + reg;
          float sv = acc[mi][mi][reg];
          if (diag) selfsim[bi * 128 + rl] = sv;
          else      possim[bi * 128 + rl] = sv;   // bi < 48 here
        }
  }
  // exp in place
#pragma unroll
  for (int mi = 0; mi < 4; ++mi)
#pragma unroll
    for (int ni = 0; ni < 4; ++ni)
#pragma unroll
      for (int reg = 0; reg < 4; ++reg)
        acc[mi][ni][reg] = exp2f(acc[mi][ni][reg] * EXP_SCALE);
  // row sums (bi rows): in-thread over ni, l16 shuffle reduce
  float rs[4][4];
#pragma unroll
  for (int mi = 0; mi < 4; ++mi)
#pragma unroll
    for (int reg = 0; reg < 4; ++reg)
      rs[mi][reg] = acc[mi][0][reg] + acc[mi][1][reg] + acc[mi][2][reg] + acc[mi][3][reg];
#pragma unroll
  for (int m = 1; m < 16; m <<= 1)
#pragma unroll
    for (int mi = 0; mi < 4; ++mi)
#pragma unroll
      for (int reg = 0; reg < 4; ++reg)
        rs[mi][reg] += __shfl_xor(rs[mi][reg], m);
  if (l16 == 0) {
#pragma unroll
    for (int mi = 0; mi < 4; ++mi)
#pragma unroll
      for (int reg = 0; reg < 4; ++reg)
        wsum[wc][wr * 64 + mi * 16 + g * 4 + reg] = rs[mi][reg];
  }
  // col sums (bj rows): in-thread over mi,reg, g shuffle reduce
  float cs[4];
#pragma unroll
  for (int ni = 0; ni < 4; ++ni) {
    float s = 0.f;
#pragma unroll
    for (int mi = 0; mi < 4; ++mi)
#pragma unroll
      for (int reg = 0; reg < 4; ++reg) s += acc[mi][ni][reg];
    s += __shfl_xor(s, 16);
    s += __shfl_xor(s, 32);
    cs[ni] = s;
  }
  if (g == 0) {
#pragma unroll
    for (int ni = 0; ni < 4; ++ni)
      csum[wr][wc * 64 + ni * 16 + l16] = cs[ni];
  }
  __syncthreads();
  if (tid < 128) {
    partial[(size_t)bj * NROWS + bi * 128 + tid] = wsum[0][tid] + wsum[1][tid];
    if (!diag)
      partial[(size_t)bi * NROWS + bj * 128 + tid] = csum[0][tid] + csum[1][tid];
  }
}

// ---------------- per-row term ----------------
__global__ __launch_bounds__(256) void finalize_terms(
    const float* __restrict__ partial, const float* __restrict__ possim,
    const float* __restrict__ selfsim, float* __restrict__ terms) {
  int i = blockIdx.x * 256 + threadIdx.x;
  float s = 0.f;
  for (int bjt = 0; bjt < NTILE; ++bjt) s += partial[(size_t)bjt * NROWS + i];
  float denom = s - exp2f(selfsim[i] * EXP_SCALE);
  float pos = possim[(i < HALF) ? i : (i - HALF)];
  terms[i] = -2.0f * pos + logf(denom);
}

// ---------------- deterministic single-block sum ----------------
__global__ __launch_bounds__(256) void finalize_sum(
    const float* __restrict__ terms, float* __restrict__ out) {
  int tid = threadIdx.x;
  float s = 0.f;
  for (int i = tid; i < NROWS; i += 256) s += terms[i];
#pragma unroll
  for (int m = 1; m < 64; m <<= 1) s += __shfl_xor(s, m);
  __shared__ float ws4[4];
  int w = tid >> 6, lane = tid & 63;
  if (lane == 0) ws4[w] = s;
  __syncthreads();
  if (tid == 0) out[0] = (ws4[0] + ws4[1] + ws4[2] + ws4[3]) / 12288.0f;
}

extern "C" void kernel_launch(void* const* d_in, const int* in_sizes, int n_in,
                              void* d_out, int out_size, void* d_ws, size_t ws_size,
                              hipStream_t stream) {
  const float* f_seq = (const float*)d_in[0];
  const float* f_spa = (const float*)d_in[1];
  const float* W     = (const float*)d_in[2];
  const float* b     = (const float*)d_in[3];
  char* ws = (char*)d_ws;
  __hip_bfloat16* Abig = (__hip_bfloat16*)ws;                // 25165824 B
  __hip_bfloat16* Wt   = (__hip_bfloat16*)(ws + 25165824);   // 1048576 B
  float* v             = (float*)(ws + 26214400);            // 25165824 B
  unsigned char* z     = (unsigned char*)ws;                 // fp8, 6291456 B (aliases dead Abig)
  float* partial       = (float*)(ws + 12582912);            // 96*12288*4 = 4718592
  float* possim        = (float*)(ws + 17301504);            // 6144*4
  float* selfsim       = (float*)(ws + 17326080);            // 12288*4
  float* terms         = (float*)(ws + 17375232);            // 12288*4
  float* out           = (float*)d_out;

  gather_convert<<<dim3(6144), dim3(256), 0, stream>>>(f_seq, f_spa, Abig);
  wt_convert<<<dim3(256), dim3(256), 0, stream>>>(W, Wt);
  proj_gemm<<<dim3(4, 96), dim3(256), 0, stream>>>(Abig, Wt, b, v);
  normalize_rows<<<dim3(12288), dim3(256), 0, stream>>>(v, z);
  sim_fused_fp8<<<dim3(NPAIR), dim3(256), 0, stream>>>(z, partial, possim, selfsim);
  finalize_terms<<<dim3(48), dim3(256), 0, stream>>>(partial, possim, selfsim, terms);
  finalize_sum<<<dim3(1), dim3(256), 0, stream>>>(terms, out);
}

// Round 8
// 133.333 us; speedup vs baseline: 2.1325x; 1.1608x over previous
//
#include <hip/hip_runtime.h>
#include <hip/hip_bf16.h>
#include <cstdint>
#include <cstddef>

#define B_DIM 2048
#define D_DIM 512
#define NROWS 12288        // 6B rows of z
#define HALF  6144         // 3B
#define NTILE 96           // 128-row tiles per dim
#define NPAIR 4656         // 96*97/2 upper-tri tiles
#define EXP_SCALE 2.8853900817779268f   // log2(e)/TEMP, TEMP=0.5

typedef __attribute__((ext_vector_type(8))) __bf16 bf16x8;
typedef __attribute__((ext_vector_type(4))) float f32x4;
typedef __attribute__((ext_vector_type(8))) int i32x8;

__device__ __forceinline__ unsigned short f2bf(float x) {
  __hip_bfloat16 h = __float2bfloat16(x);
  return *reinterpret_cast<unsigned short*>(&h);
}

__device__ __forceinline__ void gload_lds16(const void* g, void* l) {
  __builtin_amdgcn_global_load_lds(
      (const __attribute__((address_space(1))) unsigned int*)g,
      (__attribute__((address_space(3))) unsigned int*)l,
      16, 0, 0);
}

// ---- gather f -> Abig_perm bf16: [panel r/128][chunk k/8][row r%128][8] ----
__global__ __launch_bounds__(256) void gather_convert(
    const float* __restrict__ f_seq, const float* __restrict__ f_spa,
    __hip_bfloat16* __restrict__ Abig) {
  int gidx = blockIdx.x * 256 + threadIdx.x;   // 12288*128 granules
  int r = gidx >> 7;
  int c = gidx & 127;
  int k = c << 3;
  const float* f = (r < HALF) ? f_spa : f_seq;
  int rr = (r < HALF) ? r : r - HALF;
  int p = rr >> 11;
  int i = rr & 2047;
  int sel = (p == 2) ? 3 : p;
  const float* src;
  if (k < D_DIM) src = f + ((size_t)i * 4 + sel) * D_DIM + k;
  else           src = f + ((size_t)i * 4 + 2) * D_DIM + (k - D_DIM);
  float4 x0 = *(const float4*)src;
  float4 x1 = *(const float4*)(src + 4);
  uint4 o;
  o.x = (unsigned int)f2bf(x0.x) | ((unsigned int)f2bf(x0.y) << 16);
  o.y = (unsigned int)f2bf(x0.z) | ((unsigned int)f2bf(x0.w) << 16);
  o.z = (unsigned int)f2bf(x1.x) | ((unsigned int)f2bf(x1.y) << 16);
  o.w = (unsigned int)f2bf(x1.z) | ((unsigned int)f2bf(x1.w) << 16);
  *(uint4*)(Abig + (size_t)(r >> 7) * 131072 + c * 1024 + (r & 127) * 8) = o;
}

// ---- W [1024x512] -> Wt_perm: [panel n/128][chunk k/8][row n%128][8] ----
__global__ __launch_bounds__(256) void wt_convert(
    const float* __restrict__ W, __hip_bfloat16* __restrict__ Wt) {
  int gidx = blockIdx.x * 256 + threadIdx.x;   // 512*128 granules
  int n = gidx >> 7;
  int c = gidx & 127;
  int k = c << 3;
  unsigned int oo[4];
#pragma unroll
  for (int h = 0; h < 4; ++h) {
    float a = W[(size_t)(k + 2 * h) * 512 + n];
    float b = W[(size_t)(k + 2 * h + 1) * 512 + n];
    oo[h] = (unsigned int)f2bf(a) | ((unsigned int)f2bf(b) << 16);
  }
  uint4 o = {oo[0], oo[1], oo[2], oo[3]};
  *(uint4*)(Wt + (size_t)(n >> 7) * 131072 + c * 1024 + (n & 127) * 8) = o;
}

// ---- 128x128 proj tile core; panels chunk-major, fully linear staging ----
__device__ __forceinline__ void gemm_tile_128p(
    const __hip_bfloat16* Ap, const __hip_bfloat16* Bp, int nkt,
    __hip_bfloat16* As, __hip_bfloat16* Bs, f32x4 acc[4][4], int tid) {
  int w = tid >> 6, lane = tid & 63;
  int wr = w >> 1, wc = w & 1;
  int g = lane >> 4, l16 = lane & 15;
  int wb = (tid & 0xC0) * 8;
  for (int t = 0; t < nkt; ++t) {
    gload_lds16(Ap + (size_t)t * 4096 + (size_t)tid * 8,         As + wb);
    gload_lds16(Ap + (size_t)t * 4096 + (size_t)(256 + tid) * 8, As + 2048 + wb);
    gload_lds16(Bp + (size_t)t * 4096 + (size_t)tid * 8,         Bs + wb);
    gload_lds16(Bp + (size_t)t * 4096 + (size_t)(256 + tid) * 8, Bs + 2048 + wb);
    __syncthreads();
    bf16x8 af[4], bfr[4];
#pragma unroll
    for (int mi = 0; mi < 4; ++mi)
      af[mi] = *(const bf16x8*)(As + g * 1024 + (wr * 64 + mi * 16 + l16) * 8);
#pragma unroll
    for (int ni = 0; ni < 4; ++ni)
      bfr[ni] = *(const bf16x8*)(Bs + g * 1024 + (wc * 64 + ni * 16 + l16) * 8);
#pragma unroll
    for (int mi = 0; mi < 4; ++mi)
#pragma unroll
      for (int ni = 0; ni < 4; ++ni)
        acc[mi][ni] = __builtin_amdgcn_mfma_f32_16x16x32_bf16(af[mi], bfr[ni], acc[mi][ni], 0, 0, 0);
    __syncthreads();
  }
}

// ---------------- projection GEMM: v = A @ Wt^T + b  (fp32 out) ----
__global__ __launch_bounds__(256) void proj_gemm(
    const __hip_bfloat16* __restrict__ Abig, const __hip_bfloat16* __restrict__ Wt,
    const float* __restrict__ bvec, float* __restrict__ v) {
  __shared__ __align__(16) __hip_bfloat16 As[4096], Bs[4096];
  int bn = blockIdx.x, bm = blockIdx.y;
  f32x4 acc[4][4];
#pragma unroll
  for (int i = 0; i < 4; ++i)
#pragma unroll
    for (int j = 0; j < 4; ++j) acc[i][j] = (f32x4){0.f, 0.f, 0.f, 0.f};
  int tid = threadIdx.x;
  gemm_tile_128p(Abig + (size_t)bm * 131072, Wt + (size_t)bn * 131072,
                 32, As, Bs, acc, tid);
  int w = tid >> 6, lane = tid & 63, wr = w >> 1, wc = w & 1, g = lane >> 4, l16 = lane & 15;
#pragma unroll
  for (int mi = 0; mi < 4; ++mi)
#pragma unroll
    for (int ni = 0; ni < 4; ++ni)
#pragma unroll
      for (int reg = 0; reg < 4; ++reg) {
        int grow = bm * 128 + wr * 64 + mi * 16 + g * 4 + reg;
        int gcol = bn * 128 + wc * 64 + ni * 16 + l16;
        v[(size_t)grow * 512 + gcol] = acc[mi][ni][reg] + bvec[gcol];
      }
}

// -- row L2-normalize -> z fp8(e4m3), global layout = per-tile fragment image --
__global__ __launch_bounds__(256) void normalize_rows(
    const float* __restrict__ v, unsigned char* __restrict__ z) {
  int r = blockIdx.x;
  int tid = threadIdx.x;
  const float* vr = v + (size_t)r * 512;
  float2 xv = *(const float2*)(vr + tid * 2);
  float s = xv.x * xv.x + xv.y * xv.y;
#pragma unroll
  for (int m = 1; m < 64; m <<= 1) s += __shfl_xor(s, m);
  __shared__ float ws4[4];
  __shared__ float zf[512];
  int w = tid >> 6, lane = tid & 63;
  if (lane == 0) ws4[w] = s;
  __syncthreads();
  float tot = ws4[0] + ws4[1] + ws4[2] + ws4[3];
  float inv = 1.0f / fmaxf(sqrtf(tot), 1e-12f);
  zf[2 * tid]     = xv.x * inv;
  zf[2 * tid + 1] = xv.y * inv;
  __syncthreads();
  if (tid < 32) {
    int t = tid >> 3, kc = (tid >> 1) & 3, h = tid & 1;
    int k0 = t * 128 + kc * 32 + h * 16;
    unsigned int d[4];
#pragma unroll
    for (int q = 0; q < 4; ++q) {
      int pk = __builtin_amdgcn_cvt_pk_fp8_f32(zf[k0 + 4 * q],     zf[k0 + 4 * q + 1], 0, 0);
      pk     = __builtin_amdgcn_cvt_pk_fp8_f32(zf[k0 + 4 * q + 2], zf[k0 + 4 * q + 3], pk, 1);
      d[q] = (unsigned int)pk;
    }
    uint4 o = {d[0], d[1], d[2], d[3]};
    size_t off = (size_t)(r >> 7) * 65536 + (size_t)t * 16384 +
                 (size_t)((((r >> 4) & 7) * 2 + h) * 1024 + kc * 256 + (r & 15) * 16);
    *(uint4*)(z + off) = o;
  }
}

// ==== fused symmetric sim, fp8 MX, REGISTER-DIRECT, spill-free ====
// No LDS staging, no main-loop barriers. Peak live regs bounded: stage only
// B frags (8 uint4 = 32 VGPR) per K-tile; A frag loaded per-mi (8 VGPR).
// acc 64 VGPR. launch_bounds(256,3) -> ~168 VGPR cap, 12 waves/CU.
__global__ __launch_bounds__(256, 3) void sim_fused_fp8(
    const unsigned char* __restrict__ z, float* __restrict__ partial,
    float* __restrict__ possim, float* __restrict__ selfsim) {
  __shared__ float wsum[2][128];
  __shared__ float csum[2][128];

  // --- block -> (bi,bj), bi<=bj<96, supertile(12x12)-major, XCD-chunked ---
  int l = blockIdx.x;
  int q = (l & 7) * 582 + (l >> 3);
  int si = 0, sj = 0, jj = q;
  for (;;) {
    int cnt = (si == sj) ? 78 : 144;
    if (jj < cnt) break;
    jj -= cnt;
    ++sj;
    if (sj == 8) { ++si; sj = si; }
  }
  int bi, bj;
  if (si == sj) {
    int rr = 0;
    while (jj >= 12 - rr) { jj -= 12 - rr; ++rr; }
    bi = si * 12 + rr; bj = si * 12 + rr + jj;
  } else {
    bi = si * 12 + jj / 12; bj = sj * 12 + jj % 12;
  }

  int tid = threadIdx.x;
  int lane = tid & 63;
  int w = tid >> 6, wr = w >> 1, wc = w & 1;
  int g = lane >> 4, l16 = lane & 15;

  // per-lane fragment base addresses (bytes)
  const unsigned char* pA = z + (size_t)bi * 65536 + (size_t)(wr * 4) * 2048 + g * 256 + l16 * 16;
  const unsigned char* pB = z + (size_t)bj * 65536 + (size_t)(wc * 4) * 2048 + g * 256 + l16 * 16;

  f32x4 acc[4][4];
#pragma unroll
  for (int i = 0; i < 4; ++i)
#pragma unroll
    for (int j = 0; j < 4; ++j) acc[i][j] = (f32x4){0.f, 0.f, 0.f, 0.f};

#pragma unroll 1
  for (int t = 0; t < 4; ++t) {
    // stage B fragments only (32 VGPR live)
    uint4 b0[4], b1[4];
#pragma unroll
    for (int ni = 0; ni < 4; ++ni) {
      b0[ni] = *(const uint4*)(pB + t * 16384 + ni * 2048);
      b1[ni] = *(const uint4*)(pB + t * 16384 + ni * 2048 + 1024);
    }
#pragma unroll
    for (int mi = 0; mi < 4; ++mi) {
      uint4 a0 = *(const uint4*)(pA + t * 16384 + mi * 2048);
      uint4 a1 = *(const uint4*)(pA + t * 16384 + mi * 2048 + 1024);
      i32x8 aF = (i32x8){(int)a0.x, (int)a0.y, (int)a0.z, (int)a0.w,
                         (int)a1.x, (int)a1.y, (int)a1.z, (int)a1.w};
#pragma unroll
      for (int ni = 0; ni < 4; ++ni) {
        i32x8 bF = (i32x8){(int)b0[ni].x, (int)b0[ni].y, (int)b0[ni].z, (int)b0[ni].w,
                           (int)b1[ni].x, (int)b1[ni].y, (int)b1[ni].z, (int)b1[ni].w};
        acc[mi][ni] = __builtin_amdgcn_mfma_scale_f32_16x16x128_f8f6f4(
            aF, bF, acc[mi][ni], 0, 0,
            0, 0x7F7F7F7F, 0, 0x7F7F7F7F);
      }
    }
  }

  // --- epilogue (identical to verified R5/R6 version) ---
  bool diag = (bi == bj);
  bool posT = (bj == bi + 48);
  if ((diag || posT) && (wr == wc)) {
#pragma unroll
    for (int mi = 0; mi < 4; ++mi)
#pragma unroll
      for (int reg = 0; reg < 4; ++reg)
        if (l16 == g * 4 + reg) {
          int rl = wr * 64 + mi * 16 + g * 4 + reg;
          float sv = acc[mi][mi][reg];
          if (diag) selfsim[bi * 128 + rl] = sv;
          else      possim[bi * 128 + rl] = sv;   // bi < 48 here
        }
  }
  // exp in place
#pragma unroll
  for (int mi = 0; mi < 4; ++mi)
#pragma unroll
    for (int ni = 0; ni < 4; ++ni)
#pragma unroll
      for (int reg = 0; reg < 4; ++reg)
        acc[mi][ni][reg] = exp2f(acc[mi][ni][reg] * EXP_SCALE);
  // row sums (bi rows): in-thread over ni, l16 shuffle reduce
  float rs[4][4];
#pragma unroll
  for (int mi = 0; mi < 4; ++mi)
#pragma unroll
    for (int reg = 0; reg < 4; ++reg)
      rs[mi][reg] = acc[mi][0][reg] + acc[mi][1][reg] + acc[mi][2][reg] + acc[mi][3][reg];
#pragma unroll
  for (int m = 1; m < 16; m <<= 1)
#pragma unroll
    for (int mi = 0; mi < 4; ++mi)
#pragma unroll
      for (int reg = 0; reg < 4; ++reg)
        rs[mi][reg] += __shfl_xor(rs[mi][reg], m);
  if (l16 == 0) {
#pragma unroll
    for (int mi = 0; mi < 4; ++mi)
#pragma unroll
      for (int reg = 0; reg < 4; ++reg)
        wsum[wc][wr * 64 + mi * 16 + g * 4 + reg] = rs[mi][reg];
  }
  // col sums (bj rows): in-thread over mi,reg, g shuffle reduce
  float cs[4];
#pragma unroll
  for (int ni = 0; ni < 4; ++ni) {
    float s = 0.f;
#pragma unroll
    for (int mi = 0; mi < 4; ++mi)
#pragma unroll
      for (int reg = 0; reg < 4; ++reg) s += acc[mi][ni][reg];
    s += __shfl_xor(s, 16);
    s += __shfl_xor(s, 32);
    cs[ni] = s;
  }
  if (g == 0) {
#pragma unroll
    for (int ni = 0; ni < 4; ++ni)
      csum[wr][wc * 64 + ni * 16 + l16] = cs[ni];
  }
  __syncthreads();
  if (tid < 128) {
    partial[(size_t)bj * NROWS + bi * 128 + tid] = wsum[0][tid] + wsum[1][tid];
    if (!diag)
      partial[(size_t)bi * NROWS + bj * 128 + tid] = csum[0][tid] + csum[1][tid];
  }
}

// ---------------- per-row term ----------------
__global__ __launch_bounds__(256) void finalize_terms(
    const float* __restrict__ partial, const float* __restrict__ possim,
    const float* __restrict__ selfsim, float* __restrict__ terms) {
  int i = blockIdx.x * 256 + threadIdx.x;
  float s = 0.f;
  for (int bjt = 0; bjt < NTILE; ++bjt) s += partial[(size_t)bjt * NROWS + i];
  float denom = s - exp2f(selfsim[i] * EXP_SCALE);
  float pos = possim[(i < HALF) ? i : (i - HALF)];
  terms[i] = -2.0f * pos + logf(denom);
}

// ---------------- deterministic single-block sum ----------------
__global__ __launch_bounds__(256) void finalize_sum(
    const float* __restrict__ terms, float* __restrict__ out) {
  int tid = threadIdx.x;
  float s = 0.f;
  for (int i = tid; i < NROWS; i += 256) s += terms[i];
#pragma unroll
  for (int m = 1; m < 64; m <<= 1) s += __shfl_xor(s, m);
  __shared__ float ws4[4];
  int w = tid >> 6, lane = tid & 63;
  if (lane == 0) ws4[w] = s;
  __syncthreads();
  if (tid == 0) out[0] = (ws4[0] + ws4[1] + ws4[2] + ws4[3]) / 12288.0f;
}

extern "C" void kernel_launch(void* const* d_in, const int* in_sizes, int n_in,
                              void* d_out, int out_size, void* d_ws, size_t ws_size,
                              hipStream_t stream) {
  const float* f_seq = (const float*)d_in[0];
  const float* f_spa = (const float*)d_in[1];
  const float* W     = (const float*)d_in[2];
  const float* b     = (const float*)d_in[3];
  char* ws = (char*)d_ws;
  __hip_bfloat16* Abig = (__hip_bfloat16*)ws;                // 25165824 B
  __hip_bfloat16* Wt   = (__hip_bfloat16*)(ws + 25165824);   // 1048576 B
  float* v             = (float*)(ws + 26214400);            // 25165824 B
  unsigned char* z     = (unsigned char*)ws;                 // fp8, 6291456 B (aliases dead Abig)
  float* partial       = (float*)(ws + 12582912);            // 96*12288*4 = 4718592
  float* possim        = (float*)(ws + 17301504);            // 6144*4
  float* selfsim       = (float*)(ws + 17326080);            // 12288*4
  float* terms         = (float*)(ws + 17375232);            // 12288*4
  float* out           = (float*)d_out;

  gather_convert<<<dim3(6144), dim3(256), 0, stream>>>(f_seq, f_spa, Abig);
  wt_convert<<<dim3(256), dim3(256), 0, stream>>>(W, Wt);
  proj_gemm<<<dim3(4, 96), dim3(256), 0, stream>>>(Abig, Wt, b, v);
  normalize_rows<<<dim3(12288), dim3(256), 0, stream>>>(v, z);
  sim_fused_fp8<<<dim3(NPAIR), dim3(256), 0, stream>>>(z, partial, possim, selfsim);
  finalize_terms<<<dim3(48), dim3(256), 0, stream>>>(partial, possim, selfsim, terms);
  finalize_sum<<<dim3(1), dim3(256), 0, stream>>>(terms, out);
}

// Round 9
// 132.450 us; speedup vs baseline: 2.1467x; 1.0067x over previous
//
#include <hip/hip_runtime.h>
#include <hip/hip_bf16.h>
#include <cstdint>
#include <cstddef>

#define B_DIM 2048
#define D_DIM 512
#define NROWS 12288        // 6B rows of z
#define HALF  6144         // 3B
#define NTILE 96           // 128-row tiles per dim
#define NPAIR 4656         // 96*97/2 upper-tri tiles
#define EXP_SCALE 2.8853900817779268f   // log2(e)/TEMP, TEMP=0.5

typedef __attribute__((ext_vector_type(8))) __bf16 bf16x8;
typedef __attribute__((ext_vector_type(4))) float f32x4;
typedef __attribute__((ext_vector_type(8))) int i32x8;

__device__ __forceinline__ unsigned short f2bf(float x) {
  __hip_bfloat16 h = __float2bfloat16(x);
  return *reinterpret_cast<unsigned short*>(&h);
}

__device__ __forceinline__ void gload_lds16(const void* g, void* l) {
  __builtin_amdgcn_global_load_lds(
      (const __attribute__((address_space(1))) unsigned int*)g,
      (__attribute__((address_space(3))) unsigned int*)l,
      16, 0, 0);
}

// ---- gather f -> Abig_perm bf16: [panel r/128][chunk k/8][row r%128][8] ----
__global__ __launch_bounds__(256) void gather_convert(
    const float* __restrict__ f_seq, const float* __restrict__ f_spa,
    __hip_bfloat16* __restrict__ Abig) {
  int gidx = blockIdx.x * 256 + threadIdx.x;   // 12288*128 granules
  int r = gidx >> 7;
  int c = gidx & 127;
  int k = c << 3;
  const float* f = (r < HALF) ? f_spa : f_seq;
  int rr = (r < HALF) ? r : r - HALF;
  int p = rr >> 11;
  int i = rr & 2047;
  int sel = (p == 2) ? 3 : p;
  const float* src;
  if (k < D_DIM) src = f + ((size_t)i * 4 + sel) * D_DIM + k;
  else           src = f + ((size_t)i * 4 + 2) * D_DIM + (k - D_DIM);
  float4 x0 = *(const float4*)src;
  float4 x1 = *(const float4*)(src + 4);
  uint4 o;
  o.x = (unsigned int)f2bf(x0.x) | ((unsigned int)f2bf(x0.y) << 16);
  o.y = (unsigned int)f2bf(x0.z) | ((unsigned int)f2bf(x0.w) << 16);
  o.z = (unsigned int)f2bf(x1.x) | ((unsigned int)f2bf(x1.y) << 16);
  o.w = (unsigned int)f2bf(x1.z) | ((unsigned int)f2bf(x1.w) << 16);
  *(uint4*)(Abig + (size_t)(r >> 7) * 131072 + c * 1024 + (r & 127) * 8) = o;
}

// ---- W [1024x512] -> Wt_perm: [panel n/128][chunk k/8][row n%128][8] ----
__global__ __launch_bounds__(256) void wt_convert(
    const float* __restrict__ W, __hip_bfloat16* __restrict__ Wt) {
  int gidx = blockIdx.x * 256 + threadIdx.x;   // 512*128 granules
  int n = gidx >> 7;
  int c = gidx & 127;
  int k = c << 3;
  unsigned int oo[4];
#pragma unroll
  for (int h = 0; h < 4; ++h) {
    float a = W[(size_t)(k + 2 * h) * 512 + n];
    float b = W[(size_t)(k + 2 * h + 1) * 512 + n];
    oo[h] = (unsigned int)f2bf(a) | ((unsigned int)f2bf(b) << 16);
  }
  uint4 o = {oo[0], oo[1], oo[2], oo[3]};
  *(uint4*)(Wt + (size_t)(n >> 7) * 131072 + c * 1024 + (n & 127) * 8) = o;
}

// ---- 128x128 proj tile core; panels chunk-major, fully linear staging ----
__device__ __forceinline__ void gemm_tile_128p(
    const __hip_bfloat16* Ap, const __hip_bfloat16* Bp, int nkt,
    __hip_bfloat16* As, __hip_bfloat16* Bs, f32x4 acc[4][4], int tid) {
  int w = tid >> 6, lane = tid & 63;
  int wr = w >> 1, wc = w & 1;
  int g = lane >> 4, l16 = lane & 15;
  int wb = (tid & 0xC0) * 8;
  for (int t = 0; t < nkt; ++t) {
    gload_lds16(Ap + (size_t)t * 4096 + (size_t)tid * 8,         As + wb);
    gload_lds16(Ap + (size_t)t * 4096 + (size_t)(256 + tid) * 8, As + 2048 + wb);
    gload_lds16(Bp + (size_t)t * 4096 + (size_t)tid * 8,         Bs + wb);
    gload_lds16(Bp + (size_t)t * 4096 + (size_t)(256 + tid) * 8, Bs + 2048 + wb);
    __syncthreads();
    bf16x8 af[4], bfr[4];
#pragma unroll
    for (int mi = 0; mi < 4; ++mi)
      af[mi] = *(const bf16x8*)(As + g * 1024 + (wr * 64 + mi * 16 + l16) * 8);
#pragma unroll
    for (int ni = 0; ni < 4; ++ni)
      bfr[ni] = *(const bf16x8*)(Bs + g * 1024 + (wc * 64 + ni * 16 + l16) * 8);
#pragma unroll
    for (int mi = 0; mi < 4; ++mi)
#pragma unroll
      for (int ni = 0; ni < 4; ++ni)
        acc[mi][ni] = __builtin_amdgcn_mfma_f32_16x16x32_bf16(af[mi], bfr[ni], acc[mi][ni], 0, 0, 0);
    __syncthreads();
  }
}

// ---------------- projection GEMM: v = A @ Wt^T + b  (fp32 out) ----
__global__ __launch_bounds__(256) void proj_gemm(
    const __hip_bfloat16* __restrict__ Abig, const __hip_bfloat16* __restrict__ Wt,
    const float* __restrict__ bvec, float* __restrict__ v) {
  __shared__ __align__(16) __hip_bfloat16 As[4096], Bs[4096];
  int bn = blockIdx.x, bm = blockIdx.y;
  f32x4 acc[4][4];
#pragma unroll
  for (int i = 0; i < 4; ++i)
#pragma unroll
    for (int j = 0; j < 4; ++j) acc[i][j] = (f32x4){0.f, 0.f, 0.f, 0.f};
  int tid = threadIdx.x;
  gemm_tile_128p(Abig + (size_t)bm * 131072, Wt + (size_t)bn * 131072,
                 32, As, Bs, acc, tid);
  int w = tid >> 6, lane = tid & 63, wr = w >> 1, wc = w & 1, g = lane >> 4, l16 = lane & 15;
#pragma unroll
  for (int mi = 0; mi < 4; ++mi)
#pragma unroll
    for (int ni = 0; ni < 4; ++ni)
#pragma unroll
      for (int reg = 0; reg < 4; ++reg) {
        int grow = bm * 128 + wr * 64 + mi * 16 + g * 4 + reg;
        int gcol = bn * 128 + wc * 64 + ni * 16 + l16;
        v[(size_t)grow * 512 + gcol] = acc[mi][ni][reg] + bvec[gcol];
      }
}

// -- row L2-normalize -> z fp8(e4m3); per-lane-CONTIGUOUS fragment layout --
// off(r,k) = (r/128)*65536 + (k/128)*16384 + ((r>>4)&7)*2048
//            + ((k>>5)&3)*512 + (r&15)*32 + (k&31)
// => an MFMA fragment (lane l=g*16+l16: row l16 of a 16-row group,
//    k in [g*32, g*32+32)) is 32 consecutive bytes.
__global__ __launch_bounds__(256) void normalize_rows(
    const float* __restrict__ v, unsigned char* __restrict__ z) {
  int r = blockIdx.x;
  int tid = threadIdx.x;
  const float* vr = v + (size_t)r * 512;
  float2 xv = *(const float2*)(vr + tid * 2);
  float s = xv.x * xv.x + xv.y * xv.y;
#pragma unroll
  for (int m = 1; m < 64; m <<= 1) s += __shfl_xor(s, m);
  __shared__ float ws4[4];
  __shared__ float zf[512];
  int w = tid >> 6, lane = tid & 63;
  if (lane == 0) ws4[w] = s;
  __syncthreads();
  float tot = ws4[0] + ws4[1] + ws4[2] + ws4[3];
  float inv = 1.0f / fmaxf(sqrtf(tot), 1e-12f);
  zf[2 * tid]     = xv.x * inv;
  zf[2 * tid + 1] = xv.y * inv;
  __syncthreads();
  if (tid < 32) {
    int t = tid >> 3, kc = (tid >> 1) & 3, h = tid & 1;
    int k0 = t * 128 + kc * 32 + h * 16;
    unsigned int d[4];
#pragma unroll
    for (int q = 0; q < 4; ++q) {
      int pk = __builtin_amdgcn_cvt_pk_fp8_f32(zf[k0 + 4 * q],     zf[k0 + 4 * q + 1], 0, 0);
      pk     = __builtin_amdgcn_cvt_pk_fp8_f32(zf[k0 + 4 * q + 2], zf[k0 + 4 * q + 3], pk, 1);
      d[q] = (unsigned int)pk;
    }
    uint4 o = {d[0], d[1], d[2], d[3]};
    size_t off = (size_t)(r >> 7) * 65536 + (size_t)t * 16384 +
                 (size_t)(((r >> 4) & 7) * 2048 + kc * 512 + (r & 15) * 32 + h * 16);
    *(uint4*)(z + off) = o;
  }
}

// ==== fused symmetric sim, fp8 MX, REGISTER-DIRECT, mov-free fragments ====
// Each fragment = one 32B contiguous per-lane load (i32x8 deref) -> backend
// emits 2x global_load_dwordx4 into the MFMA operand tuple, no v_mov glue.
__global__ __launch_bounds__(256, 3) void sim_fused_fp8(
    const unsigned char* __restrict__ z, float* __restrict__ partial,
    float* __restrict__ possim, float* __restrict__ selfsim) {
  __shared__ float wsum[2][128];
  __shared__ float csum[2][128];

  // --- block -> (bi,bj), bi<=bj<96, supertile(12x12)-major, XCD-chunked ---
  int l = blockIdx.x;
  int q = (l & 7) * 582 + (l >> 3);
  int si = 0, sj = 0, jj = q;
  for (;;) {
    int cnt = (si == sj) ? 78 : 144;
    if (jj < cnt) break;
    jj -= cnt;
    ++sj;
    if (sj == 8) { ++si; sj = si; }
  }
  int bi, bj;
  if (si == sj) {
    int rr = 0;
    while (jj >= 12 - rr) { jj -= 12 - rr; ++rr; }
    bi = si * 12 + rr; bj = si * 12 + rr + jj;
  } else {
    bi = si * 12 + jj / 12; bj = sj * 12 + jj % 12;
  }

  int tid = threadIdx.x;
  int lane = tid & 63;
  int w = tid >> 6, wr = w >> 1, wc = w & 1;
  int g = lane >> 4, l16 = lane & 15;

  // per-lane fragment base addresses (bytes); fragment (t,frag) at
  // base + t*16384 + frag*2048, 32B contiguous per lane.
  const unsigned char* pA = z + (size_t)bi * 65536 + (size_t)(wr * 4) * 2048 + g * 512 + l16 * 32;
  const unsigned char* pB = z + (size_t)bj * 65536 + (size_t)(wc * 4) * 2048 + g * 512 + l16 * 32;

  f32x4 acc[4][4];
#pragma unroll
  for (int i = 0; i < 4; ++i)
#pragma unroll
    for (int j = 0; j < 4; ++j) acc[i][j] = (f32x4){0.f, 0.f, 0.f, 0.f};

#pragma unroll 1
  for (int t = 0; t < 4; ++t) {
    // stage B fragments (32 VGPR live), direct i32x8 loads
    i32x8 bF[4];
#pragma unroll
    for (int ni = 0; ni < 4; ++ni)
      bF[ni] = *(const i32x8*)(pB + t * 16384 + ni * 2048);
#pragma unroll
    for (int mi = 0; mi < 4; ++mi) {
      i32x8 aF = *(const i32x8*)(pA + t * 16384 + mi * 2048);
#pragma unroll
      for (int ni = 0; ni < 4; ++ni)
        acc[mi][ni] = __builtin_amdgcn_mfma_scale_f32_16x16x128_f8f6f4(
            aF, bF[ni], acc[mi][ni], 0, 0,
            0, 0x7F7F7F7F, 0, 0x7F7F7F7F);
    }
  }

  // --- epilogue (identical to verified R5-R8 version) ---
  bool diag = (bi == bj);
  bool posT = (bj == bi + 48);
  if ((diag || posT) && (wr == wc)) {
#pragma unroll
    for (int mi = 0; mi < 4; ++mi)
#pragma unroll
      for (int reg = 0; reg < 4; ++reg)
        if (l16 == g * 4 + reg) {
          int rl = wr * 64 + mi * 16 + g * 4 + reg;
          float sv = acc[mi][mi][reg];
          if (diag) selfsim[bi * 128 + rl] = sv;
          else      possim[bi * 128 + rl] = sv;   // bi < 48 here
        }
  }
  // exp in place
#pragma unroll
  for (int mi = 0; mi < 4; ++mi)
#pragma unroll
    for (int ni = 0; ni < 4; ++ni)
#pragma unroll
      for (int reg = 0; reg < 4; ++reg)
        acc[mi][ni][reg] = exp2f(acc[mi][ni][reg] * EXP_SCALE);
  // row sums (bi rows): in-thread over ni, l16 shuffle reduce
  float rs[4][4];
#pragma unroll
  for (int mi = 0; mi < 4; ++mi)
#pragma unroll
    for (int reg = 0; reg < 4; ++reg)
      rs[mi][reg] = acc[mi][0][reg] + acc[mi][1][reg] + acc[mi][2][reg] + acc[mi][3][reg];
#pragma unroll
  for (int m = 1; m < 16; m <<= 1)
#pragma unroll
    for (int mi = 0; mi < 4; ++mi)
#pragma unroll
      for (int reg = 0; reg < 4; ++reg)
        rs[mi][reg] += __shfl_xor(rs[mi][reg], m);
  if (l16 == 0) {
#pragma unroll
    for (int mi = 0; mi < 4; ++mi)
#pragma unroll
      for (int reg = 0; reg < 4; ++reg)
        wsum[wc][wr * 64 + mi * 16 + g * 4 + reg] = rs[mi][reg];
  }
  // col sums (bj rows): in-thread over mi,reg, g shuffle reduce
  float cs[4];
#pragma unroll
  for (int ni = 0; ni < 4; ++ni) {
    float s = 0.f;
#pragma unroll
    for (int mi = 0; mi < 4; ++mi)
#pragma unroll
      for (int reg = 0; reg < 4; ++reg) s += acc[mi][ni][reg];
    s += __shfl_xor(s, 16);
    s += __shfl_xor(s, 32);
    cs[ni] = s;
  }
  if (g == 0) {
#pragma unroll
    for (int ni = 0; ni < 4; ++ni)
      csum[wr][wc * 64 + ni * 16 + l16] = cs[ni];
  }
  __syncthreads();
  if (tid < 128) {
    partial[(size_t)bj * NROWS + bi * 128 + tid] = wsum[0][tid] + wsum[1][tid];
    if (!diag)
      partial[(size_t)bi * NROWS + bj * 128 + tid] = csum[0][tid] + csum[1][tid];
  }
}

// ---------------- per-row term ----------------
__global__ __launch_bounds__(256) void finalize_terms(
    const float* __restrict__ partial, const float* __restrict__ possim,
    const float* __restrict__ selfsim, float* __restrict__ terms) {
  int i = blockIdx.x * 256 + threadIdx.x;
  float s = 0.f;
  for (int bjt = 0; bjt < NTILE; ++bjt) s += partial[(size_t)bjt * NROWS + i];
  float denom = s - exp2f(selfsim[i] * EXP_SCALE);
  float pos = possim[(i < HALF) ? i : (i - HALF)];
  terms[i] = -2.0f * pos + logf(denom);
}

// ---------------- deterministic single-block sum ----------------
__global__ __launch_bounds__(256) void finalize_sum(
    const float* __restrict__ terms, float* __restrict__ out) {
  int tid = threadIdx.x;
  float s = 0.f;
  for (int i = tid; i < NROWS; i += 256) s += terms[i];
#pragma unroll
  for (int m = 1; m < 64; m <<= 1) s += __shfl_xor(s, m);
  __shared__ float ws4[4];
  int w = tid >> 6, lane = tid & 63;
  if (lane == 0) ws4[w] = s;
  __syncthreads();
  if (tid == 0) out[0] = (ws4[0] + ws4[1] + ws4[2] + ws4[3]) / 12288.0f;
}

extern "C" void kernel_launch(void* const* d_in, const int* in_sizes, int n_in,
                              void* d_out, int out_size, void* d_ws, size_t ws_size,
                              hipStream_t stream) {
  const float* f_seq = (const float*)d_in[0];
  const float* f_spa = (const float*)d_in[1];
  const float* W     = (const float*)d_in[2];
  const float* b     = (const float*)d_in[3];
  char* ws = (char*)d_ws;
  __hip_bfloat16* Abig = (__hip_bfloat16*)ws;                // 25165824 B
  __hip_bfloat16* Wt   = (__hip_bfloat16*)(ws + 25165824);   // 1048576 B
  float* v             = (float*)(ws + 26214400);            // 25165824 B
  unsigned char* z     = (unsigned char*)ws;                 // fp8, 6291456 B (aliases dead Abig)
  float* partial       = (float*)(ws + 12582912);            // 96*12288*4 = 4718592
  float* possim        = (float*)(ws + 17301504);            // 6144*4
  float* selfsim       = (float*)(ws + 17326080);            // 12288*4
  float* terms         = (float*)(ws + 17375232);            // 12288*4
  float* out           = (float*)d_out;

  gather_convert<<<dim3(6144), dim3(256), 0, stream>>>(f_seq, f_spa, Abig);
  wt_convert<<<dim3(256), dim3(256), 0, stream>>>(W, Wt);
  proj_gemm<<<dim3(4, 96), dim3(256), 0, stream>>>(Abig, Wt, b, v);
  normalize_rows<<<dim3(12288), dim3(256), 0, stream>>>(v, z);
  sim_fused_fp8<<<dim3(NPAIR), dim3(256), 0, stream>>>(z, partial, possim, selfsim);
  finalize_terms<<<dim3(48), dim3(256), 0, stream>>>(partial, possim, selfsim, terms);
  finalize_sum<<<dim3(1), dim3(256), 0, stream>>>(terms, out);
}

// Round 10
// 128.585 us; speedup vs baseline: 2.2112x; 1.0301x over previous
//
#include <hip/hip_runtime.h>
#include <hip/hip_bf16.h>
#include <cstdint>
#include <cstddef>

#define B_DIM 2048
#define D_DIM 512
#define NROWS 12288        // 6B rows of z
#define HALF  6144         // 3B
#define NTILE 96           // 128-row tiles per dim
#define NPAIR 4656         // 96*97/2 upper-tri tiles
#define EXP_SCALE 2.8853900817779268f   // log2(e)/TEMP, TEMP=0.5

typedef __attribute__((ext_vector_type(8))) __bf16 bf16x8;
typedef __attribute__((ext_vector_type(4))) float f32x4;
typedef __attribute__((ext_vector_type(8))) int i32x8;

__device__ __forceinline__ unsigned short f2bf(float x) {
  __hip_bfloat16 h = __float2bfloat16(x);
  return *reinterpret_cast<unsigned short*>(&h);
}

__device__ __forceinline__ void gload_lds16(const void* g, void* l) {
  __builtin_amdgcn_global_load_lds(
      (const __attribute__((address_space(1))) unsigned int*)g,
      (__attribute__((address_space(3))) unsigned int*)l,
      16, 0, 0);
}

// ---- merged: gather f -> Abig_perm  AND  W -> Wt_perm ----
// blocks [0,6144): gather granules; blocks [6144,6400): wt granules.
__global__ __launch_bounds__(256) void gather_convert(
    const float* __restrict__ f_seq, const float* __restrict__ f_spa,
    const float* __restrict__ W,
    __hip_bfloat16* __restrict__ Abig, __hip_bfloat16* __restrict__ Wt) {
  if (blockIdx.x < 6144) {
    int gidx = blockIdx.x * 256 + threadIdx.x;   // 12288*128 granules
    int r = gidx >> 7;
    int c = gidx & 127;
    int k = c << 3;
    const float* f = (r < HALF) ? f_spa : f_seq;
    int rr = (r < HALF) ? r : r - HALF;
    int p = rr >> 11;
    int i = rr & 2047;
    int sel = (p == 2) ? 3 : p;
    const float* src;
    if (k < D_DIM) src = f + ((size_t)i * 4 + sel) * D_DIM + k;
    else           src = f + ((size_t)i * 4 + 2) * D_DIM + (k - D_DIM);
    float4 x0 = *(const float4*)src;
    float4 x1 = *(const float4*)(src + 4);
    uint4 o;
    o.x = (unsigned int)f2bf(x0.x) | ((unsigned int)f2bf(x0.y) << 16);
    o.y = (unsigned int)f2bf(x0.z) | ((unsigned int)f2bf(x0.w) << 16);
    o.z = (unsigned int)f2bf(x1.x) | ((unsigned int)f2bf(x1.y) << 16);
    o.w = (unsigned int)f2bf(x1.z) | ((unsigned int)f2bf(x1.w) << 16);
    *(uint4*)(Abig + (size_t)(r >> 7) * 131072 + c * 1024 + (r & 127) * 8) = o;
  } else {
    int gidx = (blockIdx.x - 6144) * 256 + threadIdx.x;   // 512*128 granules
    int n = gidx >> 7;
    int c = gidx & 127;
    int k = c << 3;
    unsigned int oo[4];
#pragma unroll
    for (int h = 0; h < 4; ++h) {
      float a = W[(size_t)(k + 2 * h) * 512 + n];
      float b = W[(size_t)(k + 2 * h + 1) * 512 + n];
      oo[h] = (unsigned int)f2bf(a) | ((unsigned int)f2bf(b) << 16);
    }
    uint4 o = {oo[0], oo[1], oo[2], oo[3]};
    *(uint4*)(Wt + (size_t)(n >> 7) * 131072 + c * 1024 + (n & 127) * 8) = o;
  }
}

// ---------------- projection GEMM: 128x64 tiles, grid (8,96) ----------
// A tile: [chunk 0..3][row 0..127][8] = 8KB; B tile: [chunk 0..3][row 0..63][8]
// = 4KB. Wave grid 2x2; wave tile 64x32 (acc[4][2]).
__global__ __launch_bounds__(256, 4) void proj_gemm(
    const __hip_bfloat16* __restrict__ Abig, const __hip_bfloat16* __restrict__ Wt,
    const float* __restrict__ bvec, float* __restrict__ v) {
  __shared__ __align__(16) __hip_bfloat16 As[4096], Bs[2048];
  int bn = blockIdx.x;        // 0..7 (64-col group)
  int bm = blockIdx.y;        // 0..95
  int np = bn >> 1, nh = bn & 1;
  const __hip_bfloat16* Ap = Abig + (size_t)bm * 131072;
  const __hip_bfloat16* Bp = Wt + (size_t)np * 131072 + nh * 512;  // rows nh*64..
  int tid = threadIdx.x;
  int w = tid >> 6, lane = tid & 63;
  int wr = w >> 1, wc = w & 1;
  int g = lane >> 4, l16 = lane & 15;
  f32x4 acc[4][2];
#pragma unroll
  for (int i = 0; i < 4; ++i)
#pragma unroll
    for (int j = 0; j < 2; ++j) acc[i][j] = (f32x4){0.f, 0.f, 0.f, 0.f};

  for (int t = 0; t < 32; ++t) {
    gload_lds16(Ap + (size_t)t * 4096 + (tid >> 7) * 1024 + (tid & 127) * 8,
                As + w * 512);
    gload_lds16(Ap + (size_t)t * 4096 + 2048 + (tid >> 7) * 1024 + (tid & 127) * 8,
                As + 2048 + w * 512);
    gload_lds16(Bp + (size_t)t * 4096 + (tid >> 6) * 1024 + (tid & 63) * 8,
                Bs + w * 512);
    __syncthreads();
    bf16x8 af[4], bfr[2];
#pragma unroll
    for (int mi = 0; mi < 4; ++mi)
      af[mi] = *(const bf16x8*)(As + g * 1024 + (wr * 64 + mi * 16 + l16) * 8);
#pragma unroll
    for (int ni = 0; ni < 2; ++ni)
      bfr[ni] = *(const bf16x8*)(Bs + g * 512 + (wc * 32 + ni * 16 + l16) * 8);
#pragma unroll
    for (int mi = 0; mi < 4; ++mi)
#pragma unroll
      for (int ni = 0; ni < 2; ++ni)
        acc[mi][ni] = __builtin_amdgcn_mfma_f32_16x16x32_bf16(af[mi], bfr[ni], acc[mi][ni], 0, 0, 0);
    __syncthreads();
  }
  int grow0 = bm * 128 + wr * 64;
  int gcol0 = bn * 64 + wc * 32;
#pragma unroll
  for (int mi = 0; mi < 4; ++mi)
#pragma unroll
    for (int ni = 0; ni < 2; ++ni)
#pragma unroll
      for (int reg = 0; reg < 4; ++reg) {
        int grow = grow0 + mi * 16 + g * 4 + reg;
        int gcol = gcol0 + ni * 16 + l16;
        v[(size_t)grow * 512 + gcol] = acc[mi][ni][reg] + bvec[gcol];
      }
}

// -- row L2-normalize -> z fp8(e4m3); per-lane-CONTIGUOUS fragment layout --
// off(r,k) = (r/128)*65536 + (k/128)*16384 + ((r>>4)&7)*2048
//            + ((k>>5)&3)*512 + (r&15)*32 + (k&31)
__global__ __launch_bounds__(256) void normalize_rows(
    const float* __restrict__ v, unsigned char* __restrict__ z) {
  int r = blockIdx.x;
  int tid = threadIdx.x;
  const float* vr = v + (size_t)r * 512;
  float2 xv = *(const float2*)(vr + tid * 2);
  float s = xv.x * xv.x + xv.y * xv.y;
#pragma unroll
  for (int m = 1; m < 64; m <<= 1) s += __shfl_xor(s, m);
  __shared__ float ws4[4];
  __shared__ float zf[512];
  int w = tid >> 6, lane = tid & 63;
  if (lane == 0) ws4[w] = s;
  __syncthreads();
  float tot = ws4[0] + ws4[1] + ws4[2] + ws4[3];
  float inv = 1.0f / fmaxf(sqrtf(tot), 1e-12f);
  zf[2 * tid]     = xv.x * inv;
  zf[2 * tid + 1] = xv.y * inv;
  __syncthreads();
  if (tid < 32) {
    int t = tid >> 3, kc = (tid >> 1) & 3, h = tid & 1;
    int k0 = t * 128 + kc * 32 + h * 16;
    unsigned int d[4];
#pragma unroll
    for (int qq = 0; qq < 4; ++qq) {
      int pk = __builtin_amdgcn_cvt_pk_fp8_f32(zf[k0 + 4 * qq],     zf[k0 + 4 * qq + 1], 0, 0);
      pk     = __builtin_amdgcn_cvt_pk_fp8_f32(zf[k0 + 4 * qq + 2], zf[k0 + 4 * qq + 3], pk, 1);
      d[qq] = (unsigned int)pk;
    }
    uint4 o = {d[0], d[1], d[2], d[3]};
    size_t off = (size_t)(r >> 7) * 65536 + (size_t)t * 16384 +
                 (size_t)(((r >> 4) & 7) * 2048 + kc * 512 + (r & 15) * 32 + h * 16);
    *(uint4*)(z + off) = o;
  }
}

// ==== fused symmetric sim, fp8 MX, REGISTER-DIRECT, mov-free fragments ====
__global__ __launch_bounds__(256, 4) void sim_fused_fp8(
    const unsigned char* __restrict__ z, float* __restrict__ partial,
    float* __restrict__ possim, float* __restrict__ selfsim) {
  __shared__ float wsum[2][128];
  __shared__ float csum[2][128];

  // --- block -> (bi,bj), bi<=bj<96, supertile(12x12)-major, XCD-chunked ---
  int l = blockIdx.x;
  int q = (l & 7) * 582 + (l >> 3);
  int si = 0, sj = 0, jj = q;
  for (;;) {
    int cnt = (si == sj) ? 78 : 144;
    if (jj < cnt) break;
    jj -= cnt;
    ++sj;
    if (sj == 8) { ++si; sj = si; }
  }
  int bi, bj;
  if (si == sj) {
    int rr = 0;
    while (jj >= 12 - rr) { jj -= 12 - rr; ++rr; }
    bi = si * 12 + rr; bj = si * 12 + rr + jj;
  } else {
    bi = si * 12 + jj / 12; bj = sj * 12 + jj % 12;
  }

  int tid = threadIdx.x;
  int lane = tid & 63;
  int w = tid >> 6, wr = w >> 1, wc = w & 1;
  int g = lane >> 4, l16 = lane & 15;

  const unsigned char* pA = z + (size_t)bi * 65536 + (size_t)(wr * 4) * 2048 + g * 512 + l16 * 32;
  const unsigned char* pB = z + (size_t)bj * 65536 + (size_t)(wc * 4) * 2048 + g * 512 + l16 * 32;

  f32x4 acc[4][4];
#pragma unroll
  for (int i = 0; i < 4; ++i)
#pragma unroll
    for (int j = 0; j < 4; ++j) acc[i][j] = (f32x4){0.f, 0.f, 0.f, 0.f};

#pragma unroll 1
  for (int t = 0; t < 4; ++t) {
    i32x8 bF[4];
#pragma unroll
    for (int ni = 0; ni < 4; ++ni)
      bF[ni] = *(const i32x8*)(pB + t * 16384 + ni * 2048);
#pragma unroll
    for (int mi = 0; mi < 4; ++mi) {
      i32x8 aF = *(const i32x8*)(pA + t * 16384 + mi * 2048);
#pragma unroll
      for (int ni = 0; ni < 4; ++ni)
        acc[mi][ni] = __builtin_amdgcn_mfma_scale_f32_16x16x128_f8f6f4(
            aF, bF[ni], acc[mi][ni], 0, 0,
            0, 0x7F7F7F7F, 0, 0x7F7F7F7F);
    }
  }

  // --- epilogue (identical to verified R5-R9 version) ---
  bool diag = (bi == bj);
  bool posT = (bj == bi + 48);
  if ((diag || posT) && (wr == wc)) {
#pragma unroll
    for (int mi = 0; mi < 4; ++mi)
#pragma unroll
      for (int reg = 0; reg < 4; ++reg)
        if (l16 == g * 4 + reg) {
          int rl = wr * 64 + mi * 16 + g * 4 + reg;
          float sv = acc[mi][mi][reg];
          if (diag) selfsim[bi * 128 + rl] = sv;
          else      possim[bi * 128 + rl] = sv;   // bi < 48 here
        }
  }
  // exp in place
#pragma unroll
  for (int mi = 0; mi < 4; ++mi)
#pragma unroll
    for (int ni = 0; ni < 4; ++ni)
#pragma unroll
      for (int reg = 0; reg < 4; ++reg)
        acc[mi][ni][reg] = exp2f(acc[mi][ni][reg] * EXP_SCALE);
  // row sums (bi rows): in-thread over ni, l16 shuffle reduce
  float rs[4][4];
#pragma unroll
  for (int mi = 0; mi < 4; ++mi)
#pragma unroll
    for (int reg = 0; reg < 4; ++reg)
      rs[mi][reg] = acc[mi][0][reg] + acc[mi][1][reg] + acc[mi][2][reg] + acc[mi][3][reg];
#pragma unroll
  for (int m = 1; m < 16; m <<= 1)
#pragma unroll
    for (int mi = 0; mi < 4; ++mi)
#pragma unroll
      for (int reg = 0; reg < 4; ++reg)
        rs[mi][reg] += __shfl_xor(rs[mi][reg], m);
  if (l16 == 0) {
#pragma unroll
    for (int mi = 0; mi < 4; ++mi)
#pragma unroll
      for (int reg = 0; reg < 4; ++reg)
        wsum[wc][wr * 64 + mi * 16 + g * 4 + reg] = rs[mi][reg];
  }
  // col sums (bj rows): in-thread over mi,reg, g shuffle reduce
  float cs[4];
#pragma unroll
  for (int ni = 0; ni < 4; ++ni) {
    float s = 0.f;
#pragma unroll
    for (int mi = 0; mi < 4; ++mi)
#pragma unroll
      for (int reg = 0; reg < 4; ++reg) s += acc[mi][ni][reg];
    s += __shfl_xor(s, 16);
    s += __shfl_xor(s, 32);
    cs[ni] = s;
  }
  if (g == 0) {
#pragma unroll
    for (int ni = 0; ni < 4; ++ni)
      csum[wr][wc * 64 + ni * 16 + l16] = cs[ni];
  }
  __syncthreads();
  if (tid < 128) {
    partial[(size_t)bj * NROWS + bi * 128 + tid] = wsum[0][tid] + wsum[1][tid];
    if (!diag)
      partial[(size_t)bi * NROWS + bj * 128 + tid] = csum[0][tid] + csum[1][tid];
  }
}

// ---------------- per-row term -> per-block sums (48 floats) ----------
__global__ __launch_bounds__(256) void finalize_terms(
    const float* __restrict__ partial, const float* __restrict__ possim,
    const float* __restrict__ selfsim, float* __restrict__ blocksum) {
  int i = blockIdx.x * 256 + threadIdx.x;
  float s = 0.f;
  for (int bjt = 0; bjt < NTILE; ++bjt) s += partial[(size_t)bjt * NROWS + i];
  float denom = s - exp2f(selfsim[i] * EXP_SCALE);
  float pos = possim[(i < HALF) ? i : (i - HALF)];
  float term = -2.0f * pos + logf(denom);
#pragma unroll
  for (int m = 1; m < 64; m <<= 1) term += __shfl_xor(term, m);
  __shared__ float ws4[4];
  int tid = threadIdx.x, w = tid >> 6, lane = tid & 63;
  if (lane == 0) ws4[w] = term;
  __syncthreads();
  if (tid == 0) blocksum[blockIdx.x] = ws4[0] + ws4[1] + ws4[2] + ws4[3];
}

// ---------------- final reduce: 48 values, one wave ----------------
__global__ __launch_bounds__(64) void finalize_sum(
    const float* __restrict__ blocksum, float* __restrict__ out) {
  int tid = threadIdx.x;
  float s = (tid < 48) ? blocksum[tid] : 0.f;
#pragma unroll
  for (int m = 1; m < 64; m <<= 1) s += __shfl_xor(s, m);
  if (tid == 0) out[0] = s / 12288.0f;
}

extern "C" void kernel_launch(void* const* d_in, const int* in_sizes, int n_in,
                              void* d_out, int out_size, void* d_ws, size_t ws_size,
                              hipStream_t stream) {
  const float* f_seq = (const float*)d_in[0];
  const float* f_spa = (const float*)d_in[1];
  const float* W     = (const float*)d_in[2];
  const float* b     = (const float*)d_in[3];
  char* ws = (char*)d_ws;
  __hip_bfloat16* Abig = (__hip_bfloat16*)ws;                // 25165824 B
  __hip_bfloat16* Wt   = (__hip_bfloat16*)(ws + 25165824);   // 1048576 B
  float* v             = (float*)(ws + 26214400);            // 25165824 B
  unsigned char* z     = (unsigned char*)ws;                 // fp8, 6291456 B (aliases dead Abig)
  float* partial       = (float*)(ws + 12582912);            // 96*12288*4 = 4718592
  float* possim        = (float*)(ws + 17301504);            // 6144*4
  float* selfsim       = (float*)(ws + 17326080);            // 12288*4
  float* blocksum      = (float*)(ws + 17375232);            // 48*4
  float* out           = (float*)d_out;

  gather_convert<<<dim3(6400), dim3(256), 0, stream>>>(f_seq, f_spa, W, Abig, Wt);
  proj_gemm<<<dim3(8, 96), dim3(256), 0, stream>>>(Abig, Wt, b, v);
  normalize_rows<<<dim3(12288), dim3(256), 0, stream>>>(v, z);
  sim_fused_fp8<<<dim3(NPAIR), dim3(256), 0, stream>>>(z, partial, possim, selfsim);
  finalize_terms<<<dim3(48), dim3(256), 0, stream>>>(partial, possim, selfsim, blocksum);
  finalize_sum<<<dim3(1), dim3(64), 0, stream>>>(blocksum, out);
}

// Round 11
// 111.718 us; speedup vs baseline: 2.5451x; 1.1510x over previous
//
#include <hip/hip_runtime.h>
#include <hip/hip_bf16.h>
#include <cstdint>
#include <cstddef>

#define B_DIM 2048
#define D_DIM 512
#define NROWS 12288        // 6B rows of z
#define HALF  6144         // 3B
#define NTILE 96           // 128-row tiles per dim
#define NPAIR 4656         // 96*97/2 upper-tri tiles
#define EXP_SCALE 2.8853900817779268f   // log2(e)/TEMP, TEMP=0.5

typedef __attribute__((ext_vector_type(4))) float f32x4;
typedef __attribute__((ext_vector_type(8))) int i32x8;

// ---- merged gather: f -> A8 fp8 fragment-image, W*64 -> W8 fp8 image ----
// fragment-image layout (panel = 128 rows, K-tile = 128):
// off(r,k) = (r>>7)*131072 + (k>>7)*16384 + ((r>>4)&7)*2048
//            + ((k>>5)&3)*512 + (r&15)*32 + (k&31)
// => lane fragment (16 rows x 32 k) is 32 contiguous bytes per lane.
__global__ __launch_bounds__(256) void gather_fp8(
    const float* __restrict__ f_seq, const float* __restrict__ f_spa,
    const float* __restrict__ W,
    unsigned char* __restrict__ A8, unsigned char* __restrict__ W8) {
  int gidx = blockIdx.x * 256 + threadIdx.x;
  if (blockIdx.x < 1536) {
    int r = gidx >> 5;          // row 0..12287
    int c = gidx & 31;          // 32-elem k-chunk
    int k0 = c << 5;
    const float* f = (r < HALF) ? f_spa : f_seq;
    int rr = (r < HALF) ? r : r - HALF;
    int p = rr >> 11;
    int i = rr & 2047;
    int sel = (p == 2) ? 3 : p;
    const float* src = (k0 < D_DIM) ? f + ((size_t)i * 4 + sel) * D_DIM + k0
                                    : f + ((size_t)i * 4 + 2) * D_DIM + (k0 - D_DIM);
    unsigned int d[8];
#pragma unroll
    for (int q = 0; q < 8; ++q) {
      float4 x = *(const float4*)(src + 4 * q);
      int pk = __builtin_amdgcn_cvt_pk_fp8_f32(x.x, x.y, 0, 0);
      pk     = __builtin_amdgcn_cvt_pk_fp8_f32(x.z, x.w, pk, 1);
      d[q] = (unsigned int)pk;
    }
    size_t off = (size_t)(r >> 7) * 131072 + (size_t)(c >> 2) * 16384 +
                 (size_t)(((r >> 4) & 7) * 2048 + (c & 3) * 512 + (r & 15) * 32);
    *(uint4*)(A8 + off)      = (uint4){d[0], d[1], d[2], d[3]};
    *(uint4*)(A8 + off + 16) = (uint4){d[4], d[5], d[6], d[7]};
  } else {
    int widx = gidx - 1536 * 256;   // 0..16383
    int n = widx >> 5;              // 0..511  (output col = Wt row)
    int c = widx & 31;
    int k0 = c << 5;
    unsigned int d[8];
#pragma unroll
    for (int q = 0; q < 8; ++q) {
      float a0 = W[(size_t)(k0 + 4 * q + 0) * 512 + n] * 64.0f;
      float a1 = W[(size_t)(k0 + 4 * q + 1) * 512 + n] * 64.0f;
      float a2 = W[(size_t)(k0 + 4 * q + 2) * 512 + n] * 64.0f;
      float a3 = W[(size_t)(k0 + 4 * q + 3) * 512 + n] * 64.0f;
      int pk = __builtin_amdgcn_cvt_pk_fp8_f32(a0, a1, 0, 0);
      pk     = __builtin_amdgcn_cvt_pk_fp8_f32(a2, a3, pk, 1);
      d[q] = (unsigned int)pk;
    }
    size_t off = (size_t)(n >> 7) * 131072 + (size_t)(c >> 2) * 16384 +
                 (size_t)(((n >> 4) & 7) * 2048 + (c & 3) * 512 + (n & 15) * 32);
    *(uint4*)(W8 + off)      = (uint4){d[0], d[1], d[2], d[3]};
    *(uint4*)(W8 + off + 16) = (uint4){d[4], d[5], d[6], d[7]};
  }
}

// ---- projection GEMM fp8 MX, register-direct, barrier-free ----
// v = A @ W^T * 2^-6 (W pre-scaled x64) + b.  Block 128x64, waves 2x2
// (wave tile 64x32, acc[4][2]). K=1024 -> 8 MX K-tiles.
__global__ __launch_bounds__(256, 4) void proj_fp8(
    const unsigned char* __restrict__ A8, const unsigned char* __restrict__ W8,
    const float* __restrict__ bvec, float* __restrict__ v) {
  int bn = blockIdx.x;        // 0..7 (64-col group)
  int bm = blockIdx.y;        // 0..95 (128-row tile)
  int tid = threadIdx.x;
  int lane = tid & 63;
  int w = tid >> 6, wr = w >> 1, wc = w & 1;
  int g = lane >> 4, l16 = lane & 15;
  const unsigned char* pA = A8 + (size_t)bm * 131072 + (wr * 4) * 2048 + g * 512 + l16 * 32;
  const unsigned char* pB = W8 + (size_t)(bn >> 1) * 131072 +
                            ((bn & 1) * 4 + wc * 2) * 2048 + g * 512 + l16 * 32;
  f32x4 acc[4][2];
#pragma unroll
  for (int i = 0; i < 4; ++i)
#pragma unroll
    for (int j = 0; j < 2; ++j) acc[i][j] = (f32x4){0.f, 0.f, 0.f, 0.f};

#pragma unroll 1
  for (int t = 0; t < 8; ++t) {
    i32x8 bF[2];
#pragma unroll
    for (int ni = 0; ni < 2; ++ni)
      bF[ni] = *(const i32x8*)(pB + t * 16384 + ni * 2048);
#pragma unroll
    for (int mi = 0; mi < 4; ++mi) {
      i32x8 aF = *(const i32x8*)(pA + t * 16384 + mi * 2048);
#pragma unroll
      for (int ni = 0; ni < 2; ++ni)
        acc[mi][ni] = __builtin_amdgcn_mfma_scale_f32_16x16x128_f8f6f4(
            aF, bF[ni], acc[mi][ni], 0, 0,
            0, 0x7F7F7F7F, 0, 0x79797979);   // 2^-6 compensates W x64
    }
  }
  int grow0 = bm * 128 + wr * 64;
  int gcol0 = bn * 64 + wc * 32;
#pragma unroll
  for (int mi = 0; mi < 4; ++mi)
#pragma unroll
    for (int ni = 0; ni < 2; ++ni)
#pragma unroll
      for (int reg = 0; reg < 4; ++reg) {
        int grow = grow0 + mi * 16 + g * 4 + reg;
        int gcol = gcol0 + ni * 16 + l16;
        v[(size_t)grow * 512 + gcol] = acc[mi][ni][reg] + bvec[gcol];
      }
}

// -- row L2-normalize -> z fp8(e4m3); per-lane-CONTIGUOUS fragment layout --
__global__ __launch_bounds__(256) void normalize_rows(
    const float* __restrict__ v, unsigned char* __restrict__ z) {
  int r = blockIdx.x;
  int tid = threadIdx.x;
  const float* vr = v + (size_t)r * 512;
  float2 xv = *(const float2*)(vr + tid * 2);
  float s = xv.x * xv.x + xv.y * xv.y;
#pragma unroll
  for (int m = 1; m < 64; m <<= 1) s += __shfl_xor(s, m);
  __shared__ float ws4[4];
  __shared__ float zf[512];
  int w = tid >> 6, lane = tid & 63;
  if (lane == 0) ws4[w] = s;
  __syncthreads();
  float tot = ws4[0] + ws4[1] + ws4[2] + ws4[3];
  float inv = 1.0f / fmaxf(sqrtf(tot), 1e-12f);
  zf[2 * tid]     = xv.x * inv;
  zf[2 * tid + 1] = xv.y * inv;
  __syncthreads();
  if (tid < 32) {
    int t = tid >> 3, kc = (tid >> 1) & 3, h = tid & 1;
    int k0 = t * 128 + kc * 32 + h * 16;
    unsigned int d[4];
#pragma unroll
    for (int qq = 0; qq < 4; ++qq) {
      int pk = __builtin_amdgcn_cvt_pk_fp8_f32(zf[k0 + 4 * qq],     zf[k0 + 4 * qq + 1], 0, 0);
      pk     = __builtin_amdgcn_cvt_pk_fp8_f32(zf[k0 + 4 * qq + 2], zf[k0 + 4 * qq + 3], pk, 1);
      d[qq] = (unsigned int)pk;
    }
    uint4 o = {d[0], d[1], d[2], d[3]};
    size_t off = (size_t)(r >> 7) * 65536 + (size_t)t * 16384 +
                 (size_t)(((r >> 4) & 7) * 2048 + kc * 512 + (r & 15) * 32 + h * 16);
    *(uint4*)(z + off) = o;
  }
}

// ==== fused symmetric sim, fp8 MX, REGISTER-DIRECT, unroll-2 pipeline ====
__global__ __launch_bounds__(256, 3) void sim_fused_fp8(
    const unsigned char* __restrict__ z, float* __restrict__ partial,
    float* __restrict__ possim, float* __restrict__ selfsim) {
  __shared__ float wsum[2][128];
  __shared__ float csum[2][128];

  // --- block -> (bi,bj), bi<=bj<96, supertile(12x12)-major, XCD-chunked ---
  int l = blockIdx.x;
  int q = (l & 7) * 582 + (l >> 3);
  int si = 0, sj = 0, jj = q;
  for (;;) {
    int cnt = (si == sj) ? 78 : 144;
    if (jj < cnt) break;
    jj -= cnt;
    ++sj;
    if (sj == 8) { ++si; sj = si; }
  }
  int bi, bj;
  if (si == sj) {
    int rr = 0;
    while (jj >= 12 - rr) { jj -= 12 - rr; ++rr; }
    bi = si * 12 + rr; bj = si * 12 + rr + jj;
  } else {
    bi = si * 12 + jj / 12; bj = sj * 12 + jj % 12;
  }

  int tid = threadIdx.x;
  int lane = tid & 63;
  int w = tid >> 6, wr = w >> 1, wc = w & 1;
  int g = lane >> 4, l16 = lane & 15;

  const unsigned char* pA = z + (size_t)bi * 65536 + (size_t)(wr * 4) * 2048 + g * 512 + l16 * 32;
  const unsigned char* pB = z + (size_t)bj * 65536 + (size_t)(wc * 4) * 2048 + g * 512 + l16 * 32;

  f32x4 acc[4][4];
#pragma unroll
  for (int i = 0; i < 4; ++i)
#pragma unroll
    for (int j = 0; j < 4; ++j) acc[i][j] = (f32x4){0.f, 0.f, 0.f, 0.f};

#pragma unroll 2
  for (int t = 0; t < 4; ++t) {
    i32x8 bF[4];
#pragma unroll
    for (int ni = 0; ni < 4; ++ni)
      bF[ni] = *(const i32x8*)(pB + t * 16384 + ni * 2048);
#pragma unroll
    for (int mi = 0; mi < 4; ++mi) {
      i32x8 aF = *(const i32x8*)(pA + t * 16384 + mi * 2048);
#pragma unroll
      for (int ni = 0; ni < 4; ++ni)
        acc[mi][ni] = __builtin_amdgcn_mfma_scale_f32_16x16x128_f8f6f4(
            aF, bF[ni], acc[mi][ni], 0, 0,
            0, 0x7F7F7F7F, 0, 0x7F7F7F7F);
    }
  }

  // --- epilogue (identical to verified R5-R10 version) ---
  bool diag = (bi == bj);
  bool posT = (bj == bi + 48);
  if ((diag || posT) && (wr == wc)) {
#pragma unroll
    for (int mi = 0; mi < 4; ++mi)
#pragma unroll
      for (int reg = 0; reg < 4; ++reg)
        if (l16 == g * 4 + reg) {
          int rl = wr * 64 + mi * 16 + g * 4 + reg;
          float sv = acc[mi][mi][reg];
          if (diag) selfsim[bi * 128 + rl] = sv;
          else      possim[bi * 128 + rl] = sv;   // bi < 48 here
        }
  }
  // exp in place
#pragma unroll
  for (int mi = 0; mi < 4; ++mi)
#pragma unroll
    for (int ni = 0; ni < 4; ++ni)
#pragma unroll
      for (int reg = 0; reg < 4; ++reg)
        acc[mi][ni][reg] = exp2f(acc[mi][ni][reg] * EXP_SCALE);
  // row sums (bi rows): in-thread over ni, l16 shuffle reduce
  float rs[4][4];
#pragma unroll
  for (int mi = 0; mi < 4; ++mi)
#pragma unroll
    for (int reg = 0; reg < 4; ++reg)
      rs[mi][reg] = acc[mi][0][reg] + acc[mi][1][reg] + acc[mi][2][reg] + acc[mi][3][reg];
#pragma unroll
  for (int m = 1; m < 16; m <<= 1)
#pragma unroll
    for (int mi = 0; mi < 4; ++mi)
#pragma unroll
      for (int reg = 0; reg < 4; ++reg)
        rs[mi][reg] += __shfl_xor(rs[mi][reg], m);
  if (l16 == 0) {
#pragma unroll
    for (int mi = 0; mi < 4; ++mi)
#pragma unroll
      for (int reg = 0; reg < 4; ++reg)
        wsum[wc][wr * 64 + mi * 16 + g * 4 + reg] = rs[mi][reg];
  }
  // col sums (bj rows): in-thread over mi,reg, g shuffle reduce
  float cs[4];
#pragma unroll
  for (int ni = 0; ni < 4; ++ni) {
    float s = 0.f;
#pragma unroll
    for (int mi = 0; mi < 4; ++mi)
#pragma unroll
      for (int reg = 0; reg < 4; ++reg) s += acc[mi][ni][reg];
    s += __shfl_xor(s, 16);
    s += __shfl_xor(s, 32);
    cs[ni] = s;
  }
  if (g == 0) {
#pragma unroll
    for (int ni = 0; ni < 4; ++ni)
      csum[wr][wc * 64 + ni * 16 + l16] = cs[ni];
  }
  __syncthreads();
  if (tid < 128) {
    partial[(size_t)bj * NROWS + bi * 128 + tid] = wsum[0][tid] + wsum[1][tid];
    if (!diag)
      partial[(size_t)bi * NROWS + bj * 128 + tid] = csum[0][tid] + csum[1][tid];
  }
}

// ---------------- per-row term -> per-block sums (48 floats) ----------
__global__ __launch_bounds__(256) void finalize_terms(
    const float* __restrict__ partial, const float* __restrict__ possim,
    const float* __restrict__ selfsim, float* __restrict__ blocksum) {
  int i = blockIdx.x * 256 + threadIdx.x;
  float s = 0.f;
  for (int bjt = 0; bjt < NTILE; ++bjt) s += partial[(size_t)bjt * NROWS + i];
  float denom = s - exp2f(selfsim[i] * EXP_SCALE);
  float pos = possim[(i < HALF) ? i : (i - HALF)];
  float term = -2.0f * pos + logf(denom);
#pragma unroll
  for (int m = 1; m < 64; m <<= 1) term += __shfl_xor(term, m);
  __shared__ float ws4[4];
  int tid = threadIdx.x, w = tid >> 6, lane = tid & 63;
  if (lane == 0) ws4[w] = term;
  __syncthreads();
  if (tid == 0) blocksum[blockIdx.x] = ws4[0] + ws4[1] + ws4[2] + ws4[3];
}

// ---------------- final reduce: 48 values, one wave ----------------
__global__ __launch_bounds__(64) void finalize_sum(
    const float* __restrict__ blocksum, float* __restrict__ out) {
  int tid = threadIdx.x;
  float s = (tid < 48) ? blocksum[tid] : 0.f;
#pragma unroll
  for (int m = 1; m < 64; m <<= 1) s += __shfl_xor(s, m);
  if (tid == 0) out[0] = s / 12288.0f;
}

extern "C" void kernel_launch(void* const* d_in, const int* in_sizes, int n_in,
                              void* d_out, int out_size, void* d_ws, size_t ws_size,
                              hipStream_t stream) {
  const float* f_seq = (const float*)d_in[0];
  const float* f_spa = (const float*)d_in[1];
  const float* W     = (const float*)d_in[2];
  const float* b     = (const float*)d_in[3];
  char* ws = (char*)d_ws;
  unsigned char* A8  = (unsigned char*)ws;                   // 12,582,912 B
  unsigned char* W8  = (unsigned char*)(ws + 12582912);      // 524,288 B (dead after proj)
  float* v           = (float*)(ws + 26214400);              // 25,165,824 B
  unsigned char* z   = (unsigned char*)ws;                   // 6,291,456 B (aliases dead A8)
  float* partial     = (float*)(ws + 12582912);              // 4,718,592 B (aliases dead W8)
  float* possim      = (float*)(ws + 17301504);              // 6144*4
  float* selfsim     = (float*)(ws + 17326080);              // 12288*4
  float* blocksum    = (float*)(ws + 17375232);              // 48*4
  float* out         = (float*)d_out;

  gather_fp8<<<dim3(1600), dim3(256), 0, stream>>>(f_seq, f_spa, W, A8, W8);
  proj_fp8<<<dim3(8, 96), dim3(256), 0, stream>>>(A8, W8, b, v);
  normalize_rows<<<dim3(12288), dim3(256), 0, stream>>>(v, z);
  sim_fused_fp8<<<dim3(NPAIR), dim3(256), 0, stream>>>(z, partial, possim, selfsim);
  finalize_terms<<<dim3(48), dim3(256), 0, stream>>>(partial, possim, selfsim, blocksum);
  finalize_sum<<<dim3(1), dim3(64), 0, stream>>>(blocksum, out);
}